// Round 1
// baseline (1197.395 us; speedup 1.0000x reference)
//
#include <hip/hip_runtime.h>
#include <math.h>

#define TILE 64
#define BK 16

// Generic tiled fp32 GEMM: C[M,N] = alpha * A[M,K] @ op(B) (+ bias)
// TRANS_B: B stored [N,K] (NT, used for Q@K^T); else B stored [K,N] (NN).
// grid.z = batch, with per-batch element strides sA/sB/sC.
template<bool TRANS_B, bool HAS_BIAS>
__global__ __launch_bounds__(256)
void gemm_tile(const float* __restrict__ A, const float* __restrict__ Bm,
               const float* __restrict__ bias, float* __restrict__ Cm,
               int M, int N, int K, float alpha,
               long sA, long sB, long sC)
{
    // As[m][k], Bs[n][k]; +1 pad -> compute-phase reads are 2-way aliased (free on gfx950)
    __shared__ float As[TILE][BK + 1];
    __shared__ float Bs[TILE][BK + 1];

    const int bz = blockIdx.z;
    const float* Ab = A + (long)bz * sA;
    const float* Bb = Bm + (long)bz * sB;
    float* Cb = Cm + (long)bz * sC;

    const int m0 = blockIdx.y * TILE;
    const int n0 = blockIdx.x * TILE;
    const int tid = threadIdx.x;
    const int tx = tid & 15;   // -> 4 output cols
    const int ty = tid >> 4;   // -> 4 output rows

    float acc[4][4] = {};

    for (int k0 = 0; k0 < K; k0 += BK) {
        // A tile 64x16, float4 per thread, coalesced
        {
            const int m = tid >> 2;
            const int k = (tid & 3) * 4;
            const float4 v = *(const float4*)(Ab + (long)(m0 + m) * K + k0 + k);
            As[m][k + 0] = v.x; As[m][k + 1] = v.y;
            As[m][k + 2] = v.z; As[m][k + 3] = v.w;
        }
        if (TRANS_B) {
            // B[N,K]: same pattern as A
            const int n = tid >> 2;
            const int k = (tid & 3) * 4;
            const float4 v = *(const float4*)(Bb + (long)(n0 + n) * K + k0 + k);
            Bs[n][k + 0] = v.x; Bs[n][k + 1] = v.y;
            Bs[n][k + 2] = v.z; Bs[n][k + 3] = v.w;
        } else {
            // B[K,N]: rows k0..k0+15, cols n0..n0+63; store transposed into Bs[n][k]
            const int kr = tid >> 4;
            const int nc = (tid & 15) * 4;
            const float4 v = *(const float4*)(Bb + (long)(k0 + kr) * N + n0 + nc);
            Bs[nc + 0][kr] = v.x; Bs[nc + 1][kr] = v.y;
            Bs[nc + 2][kr] = v.z; Bs[nc + 3][kr] = v.w;
        }
        __syncthreads();

        #pragma unroll
        for (int kk = 0; kk < BK; ++kk) {
            float a[4], b[4];
            #pragma unroll
            for (int r = 0; r < 4; ++r) a[r] = As[ty * 4 + r][kk];
            #pragma unroll
            for (int c = 0; c < 4; ++c) b[c] = Bs[tx * 4 + c][kk];
            #pragma unroll
            for (int r = 0; r < 4; ++r)
                #pragma unroll
                for (int c = 0; c < 4; ++c)
                    acc[r][c] = fmaf(a[r], b[c], acc[r][c]);
        }
        __syncthreads();
    }

    #pragma unroll
    for (int r = 0; r < 4; ++r) {
        const int m = m0 + ty * 4 + r;
        #pragma unroll
        for (int c = 0; c < 4; ++c) {
            const int n = n0 + tx * 4 + c;
            float v = acc[r][c] * alpha;
            if (HAS_BIAS) v += bias[n];
            Cb[(long)m * N + n] = v;
        }
    }
}

// One block (256 threads) per row of length 2048; in-place softmax.
__global__ __launch_bounds__(256)
void softmax_rows(float* __restrict__ S)
{
    const int Lk = 2048;
    float* row = S + (long)blockIdx.x * Lk;
    const int tid = threadIdx.x;

    float4 v0 = *(float4*)(row + tid * 4);
    float4 v1 = *(float4*)(row + 1024 + tid * 4);
    float x[8] = { v0.x, v0.y, v0.z, v0.w, v1.x, v1.y, v1.z, v1.w };

    __shared__ float red[4];

    // --- max ---
    float lm = x[0];
    #pragma unroll
    for (int i = 1; i < 8; ++i) lm = fmaxf(lm, x[i]);
    #pragma unroll
    for (int off = 32; off > 0; off >>= 1) lm = fmaxf(lm, __shfl_down(lm, off));
    if ((tid & 63) == 0) red[tid >> 6] = lm;
    __syncthreads();
    if (tid == 0) {
        float mm = fmaxf(fmaxf(red[0], red[1]), fmaxf(red[2], red[3]));
        red[0] = mm;
    }
    __syncthreads();
    const float rowmax = red[0];
    __syncthreads();

    // --- exp + sum ---
    float ls = 0.f;
    #pragma unroll
    for (int i = 0; i < 8; ++i) { x[i] = __expf(x[i] - rowmax); ls += x[i]; }
    #pragma unroll
    for (int off = 32; off > 0; off >>= 1) ls += __shfl_down(ls, off);
    if ((tid & 63) == 0) red[tid >> 6] = ls;
    __syncthreads();
    if (tid == 0) red[0] = red[0] + red[1] + red[2] + red[3];
    __syncthreads();
    const float inv = 1.0f / red[0];

    v0 = make_float4(x[0] * inv, x[1] * inv, x[2] * inv, x[3] * inv);
    v1 = make_float4(x[4] * inv, x[5] * inv, x[6] * inv, x[7] * inv);
    *(float4*)(row + tid * 4) = v0;
    *(float4*)(row + 1024 + tid * 4) = v1;
}

extern "C" void kernel_launch(void* const* d_in, const int* in_sizes, int n_in,
                              void* d_out, int out_size, void* d_ws, size_t ws_size,
                              hipStream_t stream) {
    const float* query = (const float*)d_in[0];
    const float* key   = (const float*)d_in[1];
    const float* value = (const float*)d_in[2];
    const float* Wq    = (const float*)d_in[3];
    const float* bq    = (const float*)d_in[4];
    const float* Wk    = (const float*)d_in[5];
    const float* bk    = (const float*)d_in[6];
    const float* Wv    = (const float*)d_in[7];
    const float* bv    = (const float*)d_in[8];
    const float* Wo    = (const float*)d_in[9];
    const float* bo    = (const float*)d_in[10];
    float* out = (float*)d_out;

    const int B = 4, L = 2048, C = 512;
    const long BLC = (long)B * L * C;   // 4,194,304
    const long BLL = (long)B * L * L;   // 16,777,216

    float* ws = (float*)d_ws;
    float* Qp = ws;
    float* Kp = Qp + BLC;
    float* Vp = Kp + BLC;
    float* S  = Vp + BLC;
    float* O  = S + BLL;
    // total ws: 3*BLC + BLL + BLC = 33.6M floats = 134.2 MB

    const dim3 blk(256);
    const float scale = 1.0f / sqrtf((float)C);

    // projections: M = B*L = 8192, N = K = 512 (batches are contiguous -> fold into M)
    const dim3 gproj(C / TILE, (B * L) / TILE, 1);
    gemm_tile<false, true><<<gproj, blk, 0, stream>>>(query, Wq, bq, Qp, B * L, C, C, 1.0f, 0, 0, 0);
    gemm_tile<false, true><<<gproj, blk, 0, stream>>>(key,   Wk, bk, Kp, B * L, C, C, 1.0f, 0, 0, 0);
    gemm_tile<false, true><<<gproj, blk, 0, stream>>>(value, Wv, bv, Vp, B * L, C, C, 1.0f, 0, 0, 0);

    // scores: S[b] = scale * Q[b] @ K[b]^T   (M=N=2048, K=512)
    const dim3 gsc(L / TILE, L / TILE, B);
    gemm_tile<true, false><<<gsc, blk, 0, stream>>>(Qp, Kp, nullptr, S, L, L, C, scale,
                                                    (long)L * C, (long)L * C, (long)L * L);

    // softmax over last dim, in place
    softmax_rows<<<dim3(B * L), blk, 0, stream>>>(S);

    // O[b] = P[b] @ V[b]   (M=2048, N=512, K=2048)
    const dim3 gpv(C / TILE, L / TILE, B);
    gemm_tile<false, false><<<gpv, blk, 0, stream>>>(S, Vp, nullptr, O, L, C, L, 1.0f,
                                                     (long)L * L, (long)L * C, (long)L * C);

    // out = O @ Wo + bo  (M=8192, N=K=512)
    gemm_tile<false, true><<<gproj, blk, 0, stream>>>(O, Wo, bo, out, B * L, C, C, 1.0f, 0, 0, 0);
}

// Round 3
// 434.452 us; speedup vs baseline: 2.7561x; 2.7561x over previous
//
#include <hip/hip_runtime.h>
#include <math.h>

typedef __attribute__((ext_vector_type(8))) short bf16x8;
typedef __attribute__((ext_vector_type(4))) float f32x4;

__device__ __forceinline__ unsigned short f2bf(float x) {
    union { float f; unsigned u; } v; v.f = x;
    unsigned r = v.u + 0x7FFFu + ((v.u >> 16) & 1u);   // RNE
    return (unsigned short)(r >> 16);
}
__device__ __forceinline__ float bf2f(unsigned short h) {
    union { float f; unsigned u; } v; v.u = ((unsigned)h) << 16; return v.f;
}

// ---------------------------------------------------------------------------
// fp32 -> (hi, lo) bf16 split, elementwise (layout preserved). n4 = count/4.
__global__ __launch_bounds__(256)
void split_rows(const float* __restrict__ src, unsigned short* __restrict__ dhi,
                unsigned short* __restrict__ dlo, long n4)
{
    long i = (long)blockIdx.x * 256 + threadIdx.x;
    if (i >= n4) return;
    float4 v = ((const float4*)src)[i];
    ushort4 h, l;
    h.x = f2bf(v.x); l.x = f2bf(v.x - bf2f(h.x));
    h.y = f2bf(v.y); l.y = f2bf(v.y - bf2f(h.y));
    h.z = f2bf(v.z); l.z = f2bf(v.z - bf2f(h.z));
    h.w = f2bf(v.w); l.w = f2bf(v.w - bf2f(h.w));
    ((ushort4*)dhi)[i] = h;
    ((ushort4*)dlo)[i] = l;
}

// ---------------------------------------------------------------------------
// Transpose + split: src fp32 [R][Cc] -> dst_hi/lo bf16 [Cc][R].
// grid (Cc/32, R/32, batch); strides in elements.
__global__ __launch_bounds__(256)
void transpose_split(const float* __restrict__ src, unsigned short* __restrict__ dhi,
                     unsigned short* __restrict__ dlo, int R, int Cc, long sSrc, long sDst)
{
    __shared__ float T[32][33];
    const float* s = src + (long)blockIdx.z * sSrc;
    const int r0 = blockIdx.y * 32, c0 = blockIdx.x * 32;
    const int t = threadIdx.x;
    {
        const int r = t >> 3, cq = (t & 7) * 4;
        float4 v = *(const float4*)(s + (long)(r0 + r) * Cc + c0 + cq);
        T[r][cq] = v.x; T[r][cq + 1] = v.y; T[r][cq + 2] = v.z; T[r][cq + 3] = v.w;
    }
    __syncthreads();
    {
        const int c = t >> 3, rq = (t & 7) * 4;
        float x0 = T[rq][c], x1 = T[rq + 1][c], x2 = T[rq + 2][c], x3 = T[rq + 3][c];
        ushort4 h, l;
        h.x = f2bf(x0); l.x = f2bf(x0 - bf2f(h.x));
        h.y = f2bf(x1); l.y = f2bf(x1 - bf2f(h.y));
        h.z = f2bf(x2); l.z = f2bf(x2 - bf2f(h.z));
        h.w = f2bf(x3); l.w = f2bf(x3 - bf2f(h.w));
        long o = (long)blockIdx.z * sDst + (long)(c0 + c) * R + r0 + rq;
        *(ushort4*)(dhi + o) = h;
        *(ushort4*)(dlo + o) = l;
    }
}

// ---------------------------------------------------------------------------
// Split-bf16 MFMA GEMM, NT: C[M,N] = alpha*(A @ B^T) (+bias), A=[M][K], B=[N][K]
// (both as hi/lo bf16 arrays with row strides lda/ldb in elements).
// EPI 0: fp32 out. EPI 1: hi/lo bf16 out. 128x128 tile, BK=32, 256 thr (4 waves).
template<int EPI>
__global__ __launch_bounds__(256)
void gemm_nt_split(const unsigned short* __restrict__ Ah_g, const unsigned short* __restrict__ Al_g,
                   const unsigned short* __restrict__ Bh_g, const unsigned short* __restrict__ Bl_g,
                   const float* __restrict__ bias,
                   float* __restrict__ Cf, unsigned short* __restrict__ Chi, unsigned short* __restrict__ Clo,
                   int K, int lda, int ldb, int ldc, float alpha,
                   long sA, long sB, long sC)
{
    // +8 pad: 80B row stride keeps ds_read_b128 16B-aligned, <=2-way bank alias
    __shared__ __align__(16) unsigned short Ah[128][40], Al[128][40];
    __shared__ __align__(16) unsigned short Bh[128][40], Bl[128][40];

    const int tid = threadIdx.x;
    const int m0 = blockIdx.y * 128, n0 = blockIdx.x * 128;
    const long zb = blockIdx.z;
    const unsigned short* pAh = Ah_g + zb * sA;
    const unsigned short* pAl = Al_g + zb * sA;
    const unsigned short* pBh = Bh_g + zb * sB;
    const unsigned short* pBl = Bl_g + zb * sB;

    const int w = tid >> 6, lane = tid & 63;
    const int wr = w >> 1, wc = w & 1;
    const int quad = lane >> 4, mr = lane & 15;

    f32x4 acc[4][4] = {};

    // staging: 128 rows x 32 cols per array = 512 x 16B chunks; 256 threads
    // stage TWO 16B chunks per array: row = tid>>1, cols [scol, scol+16).
    const int srow = tid >> 1, scol = (tid & 1) * 16;

    for (int k0 = 0; k0 < K; k0 += 32) {
        const long ga = (long)(m0 + srow) * lda + k0 + scol;
        const long gb = (long)(n0 + srow) * ldb + k0 + scol;
        bf16x8 vah0 = *(const bf16x8*)(pAh + ga);
        bf16x8 vah1 = *(const bf16x8*)(pAh + ga + 8);
        bf16x8 val0 = *(const bf16x8*)(pAl + ga);
        bf16x8 val1 = *(const bf16x8*)(pAl + ga + 8);
        bf16x8 vbh0 = *(const bf16x8*)(pBh + gb);
        bf16x8 vbh1 = *(const bf16x8*)(pBh + gb + 8);
        bf16x8 vbl0 = *(const bf16x8*)(pBl + gb);
        bf16x8 vbl1 = *(const bf16x8*)(pBl + gb + 8);
        *(bf16x8*)&Ah[srow][scol]     = vah0;
        *(bf16x8*)&Ah[srow][scol + 8] = vah1;
        *(bf16x8*)&Al[srow][scol]     = val0;
        *(bf16x8*)&Al[srow][scol + 8] = val1;
        *(bf16x8*)&Bh[srow][scol]     = vbh0;
        *(bf16x8*)&Bh[srow][scol + 8] = vbh1;
        *(bf16x8*)&Bl[srow][scol]     = vbl0;
        *(bf16x8*)&Bl[srow][scol + 8] = vbl1;
        __syncthreads();

        bf16x8 afh[4], afl[4], bfh[4], bfl[4];
        #pragma unroll
        for (int r = 0; r < 4; ++r) {
            const int ar = wr * 64 + r * 16 + mr;
            afh[r] = *(const bf16x8*)&Ah[ar][quad * 8];
            afl[r] = *(const bf16x8*)&Al[ar][quad * 8];
            const int br = wc * 64 + r * 16 + mr;
            bfh[r] = *(const bf16x8*)&Bh[br][quad * 8];
            bfl[r] = *(const bf16x8*)&Bl[br][quad * 8];
        }
        #pragma unroll
        for (int r = 0; r < 4; ++r)
            #pragma unroll
            for (int c = 0; c < 4; ++c) {
                acc[r][c] = __builtin_amdgcn_mfma_f32_16x16x32_bf16(afh[r], bfh[c], acc[r][c], 0, 0, 0);
                acc[r][c] = __builtin_amdgcn_mfma_f32_16x16x32_bf16(afh[r], bfl[c], acc[r][c], 0, 0, 0);
                acc[r][c] = __builtin_amdgcn_mfma_f32_16x16x32_bf16(afl[r], bfh[c], acc[r][c], 0, 0, 0);
            }
        __syncthreads();
    }

    // epilogue: C/D layout col=lane&15, row=quad*4+reg  [verified m89/m91]
    #pragma unroll
    for (int r = 0; r < 4; ++r) {
        #pragma unroll
        for (int c = 0; c < 4; ++c) {
            const int col = n0 + wc * 64 + c * 16 + mr;
            const float bv = bias ? bias[col] : 0.0f;
            #pragma unroll
            for (int e = 0; e < 4; ++e) {
                const int rowg = m0 + wr * 64 + r * 16 + quad * 4 + e;
                const float v = acc[r][c][e] * alpha + bv;
                const long off = zb * sC + (long)rowg * ldc + col;
                if (EPI == 0) {
                    Cf[off] = v;
                } else {
                    const unsigned short h = f2bf(v);
                    Chi[off] = h;
                    Clo[off] = f2bf(v - bf2f(h));
                }
            }
        }
    }
}

// ---------------------------------------------------------------------------
// Softmax over rows of 2048 fp32, writing P as hi/lo bf16 IN PLACE over the row:
// bytes [0,4096) = P_hi[2048], bytes [4096,8192) = P_lo[2048].
__global__ __launch_bounds__(256)
void softmax_rows_hl(float* __restrict__ S)
{
    float* row = S + (long)blockIdx.x * 2048;
    const int tid = threadIdx.x;

    float4 v0 = *(float4*)(row + tid * 4);
    float4 v1 = *(float4*)(row + 1024 + tid * 4);
    float x[8] = { v0.x, v0.y, v0.z, v0.w, v1.x, v1.y, v1.z, v1.w };

    __shared__ float red[4];

    float lm = x[0];
    #pragma unroll
    for (int i = 1; i < 8; ++i) lm = fmaxf(lm, x[i]);
    #pragma unroll
    for (int off = 32; off > 0; off >>= 1) lm = fmaxf(lm, __shfl_down(lm, off));
    if ((tid & 63) == 0) red[tid >> 6] = lm;
    __syncthreads();
    if (tid == 0) red[0] = fmaxf(fmaxf(red[0], red[1]), fmaxf(red[2], red[3]));
    __syncthreads();
    const float rowmax = red[0];
    __syncthreads();

    float ls = 0.f;
    #pragma unroll
    for (int i = 0; i < 8; ++i) { x[i] = __expf(x[i] - rowmax); ls += x[i]; }
    #pragma unroll
    for (int off = 32; off > 0; off >>= 1) ls += __shfl_down(ls, off);
    if ((tid & 63) == 0) red[tid >> 6] = ls;
    __syncthreads();
    if (tid == 0) red[0] = red[0] + red[1] + red[2] + red[3];
    __syncthreads();
    const float inv = 1.0f / red[0];
    // all row reads happened before the barriers above -> safe to overwrite

    unsigned short* ph = (unsigned short*)row;
    unsigned short* pl = ph + 2048;
    ushort4 h0, l0, h1, l1;
    float y;
    y = x[0] * inv; h0.x = f2bf(y); l0.x = f2bf(y - bf2f(h0.x));
    y = x[1] * inv; h0.y = f2bf(y); l0.y = f2bf(y - bf2f(h0.y));
    y = x[2] * inv; h0.z = f2bf(y); l0.z = f2bf(y - bf2f(h0.z));
    y = x[3] * inv; h0.w = f2bf(y); l0.w = f2bf(y - bf2f(h0.w));
    y = x[4] * inv; h1.x = f2bf(y); l1.x = f2bf(y - bf2f(h1.x));
    y = x[5] * inv; h1.y = f2bf(y); l1.y = f2bf(y - bf2f(h1.y));
    y = x[6] * inv; h1.z = f2bf(y); l1.z = f2bf(y - bf2f(h1.z));
    y = x[7] * inv; h1.w = f2bf(y); l1.w = f2bf(y - bf2f(h1.w));
    *(ushort4*)(ph + tid * 4) = h0;
    *(ushort4*)(ph + 1024 + tid * 4) = h1;
    *(ushort4*)(pl + tid * 4) = l0;
    *(ushort4*)(pl + 1024 + tid * 4) = l1;
}

// ---------------------------------------------------------------------------
extern "C" void kernel_launch(void* const* d_in, const int* in_sizes, int n_in,
                              void* d_out, int out_size, void* d_ws, size_t ws_size,
                              hipStream_t stream) {
    const float* query = (const float*)d_in[0];
    const float* key   = (const float*)d_in[1];
    const float* value = (const float*)d_in[2];
    const float* Wq    = (const float*)d_in[3];
    const float* bq    = (const float*)d_in[4];
    const float* Wk    = (const float*)d_in[5];
    const float* bk    = (const float*)d_in[6];
    const float* Wv    = (const float*)d_in[7];
    const float* bv    = (const float*)d_in[8];
    const float* Wo    = (const float*)d_in[9];
    const float* bo    = (const float*)d_in[10];
    float* out = (float*)d_out;

    const int B = 4, L = 2048, C = 512;
    const int M = B * L;               // 8192
    char* ws = (char*)d_ws;

    // ---- workspace map (bytes) --------------------------------------------
    // [0, 4M):        WT hi/lo for Wq,Wk,Wv,Wo  (each 512KB)
    // [4M, 20.8M):    Q_hi, Q_lo   (later reused for O_hi, O_lo)
    // [20.8M, 37.5M): K_hi, K_lo
    // [37.5M, 54.3M): VT_hi, VT_lo
    // [54.3M, 121.6M): S fp32 (in-place -> P hi/lo). Before S is written this
    //                  region hosts: in_hi/in_lo scratch + Vp fp32.
    unsigned short* WqT_h = (unsigned short*)(ws);
    unsigned short* WqT_l = (unsigned short*)(ws + 524288);
    unsigned short* WkT_h = (unsigned short*)(ws + 1048576);
    unsigned short* WkT_l = (unsigned short*)(ws + 1572864);
    unsigned short* WvT_h = (unsigned short*)(ws + 2097152);
    unsigned short* WvT_l = (unsigned short*)(ws + 2621440);
    unsigned short* WoT_h = (unsigned short*)(ws + 3145728);
    unsigned short* WoT_l = (unsigned short*)(ws + 3670016);
    unsigned short* Q_h   = (unsigned short*)(ws + 4194304);
    unsigned short* Q_l   = (unsigned short*)(ws + 12582912);
    unsigned short* K_h   = (unsigned short*)(ws + 20971520);
    unsigned short* K_l   = (unsigned short*)(ws + 29360128);
    unsigned short* VT_h  = (unsigned short*)(ws + 37748736);
    unsigned short* VT_l  = (unsigned short*)(ws + 46137344);
    float*          S     = (float*)(ws + 54525952);
    unsigned short* in_h  = (unsigned short*)(ws + 54525952);
    unsigned short* in_l  = (unsigned short*)(ws + 62914560);
    float*          Vp    = (float*)(ws + 71303168);
    unsigned short* O_h   = Q_h;   // Q dead after QK^T
    unsigned short* O_l   = Q_l;

    const dim3 blk(256);
    const float scale = 1.0f / sqrtf((float)C);
    const long LC = (long)L * C;      // 1,048,576
    const long LL = (long)L * L;      // 4,194,304

    // 1) weights: W [in][out] -> WT hi/lo [out][in]
    transpose_split<<<dim3(16, 16, 1), blk, 0, stream>>>(Wq, WqT_h, WqT_l, C, C, 0, 0);
    transpose_split<<<dim3(16, 16, 1), blk, 0, stream>>>(Wk, WkT_h, WkT_l, C, C, 0, 0);
    transpose_split<<<dim3(16, 16, 1), blk, 0, stream>>>(Wv, WvT_h, WvT_l, C, C, 0, 0);
    transpose_split<<<dim3(16, 16, 1), blk, 0, stream>>>(Wo, WoT_h, WoT_l, C, C, 0, 0);

    const long n4 = (long)M * C / 4;
    const dim3 gsplit((unsigned)((n4 + 255) / 256));
    const dim3 gproj(C / 128, M / 128, 1);          // (4, 64)

    // 2) Q = query @ Wq^T + bq  -> hi/lo
    split_rows<<<gsplit, blk, 0, stream>>>(query, in_h, in_l, n4);
    gemm_nt_split<1><<<gproj, blk, 0, stream>>>(in_h, in_l, WqT_h, WqT_l, bq,
        nullptr, Q_h, Q_l, C, C, C, C, 1.0f, 0, 0, 0);
    // 3) K
    split_rows<<<gsplit, blk, 0, stream>>>(key, in_h, in_l, n4);
    gemm_nt_split<1><<<gproj, blk, 0, stream>>>(in_h, in_l, WkT_h, WkT_l, bk,
        nullptr, K_h, K_l, C, C, C, C, 1.0f, 0, 0, 0);
    // 4) V -> fp32 Vp, then transpose-split to VT hi/lo [C][L] per batch
    split_rows<<<gsplit, blk, 0, stream>>>(value, in_h, in_l, n4);
    gemm_nt_split<0><<<gproj, blk, 0, stream>>>(in_h, in_l, WvT_h, WvT_l, bv,
        Vp, nullptr, nullptr, C, C, C, C, 1.0f, 0, 0, 0);
    transpose_split<<<dim3(16, 64, 4), blk, 0, stream>>>(Vp, VT_h, VT_l, L, C, LC, LC);

    // 5) S = scale * Q @ K^T   (per batch), fp32
    gemm_nt_split<0><<<dim3(16, 16, 4), blk, 0, stream>>>(Q_h, Q_l, K_h, K_l, nullptr,
        S, nullptr, nullptr, C, C, C, L, scale, LC, LC, LL);

    // 6) softmax -> P hi/lo in place (row = 4096 ushorts: hi[2048] then lo[2048])
    softmax_rows_hl<<<dim3(M), blk, 0, stream>>>(S);

    // 7) O = P @ V = P @ (VT)^T -> hi/lo (over dead Q region)
    gemm_nt_split<1><<<dim3(4, 16, 4), blk, 0, stream>>>(
        (unsigned short*)S, (unsigned short*)S + 2048, VT_h, VT_l, nullptr,
        nullptr, O_h, O_l, L, 4096, L, C, 1.0f, (long)L * 4096, LC, LC);

    // 8) out = O @ Wo^T + bo, fp32
    gemm_nt_split<0><<<gproj, blk, 0, stream>>>(O_h, O_l, WoT_h, WoT_l, bo,
        out, nullptr, nullptr, C, C, C, C, 1.0f, 0, 0, 0);
}

// Round 4
// 368.959 us; speedup vs baseline: 3.2453x; 1.1775x over previous
//
#include <hip/hip_runtime.h>
#include <math.h>

typedef __attribute__((ext_vector_type(8))) short bf16x8;
typedef __attribute__((ext_vector_type(4))) float f32x4;

__device__ __forceinline__ unsigned short f2bf(float x) {
    union { float f; unsigned u; } v; v.f = x;
    unsigned r = v.u + 0x7FFFu + ((v.u >> 16) & 1u);   // RNE
    return (unsigned short)(r >> 16);
}
__device__ __forceinline__ float bf2f(unsigned short h) {
    union { float f; unsigned u; } v; v.u = ((unsigned)h) << 16; return v.f;
}

// ---------------------------------------------------------------------------
// 3 input tensors -> hi/lo split, one dispatch (grid.z selects tensor).
struct Split3Args {
    const float* src[3];
    unsigned short* dh[3];
    unsigned short* dl[3];
};
__global__ __launch_bounds__(256)
void split_rows3(Split3Args a, long n4)
{
    const int z = blockIdx.z;
    long i = (long)blockIdx.x * 256 + threadIdx.x;
    if (i >= n4) return;
    float4 v = ((const float4*)a.src[z])[i];
    ushort4 h, l;
    h.x = f2bf(v.x); l.x = f2bf(v.x - bf2f(h.x));
    h.y = f2bf(v.y); l.y = f2bf(v.y - bf2f(h.y));
    h.z = f2bf(v.z); l.z = f2bf(v.z - bf2f(h.z));
    h.w = f2bf(v.w); l.w = f2bf(v.w - bf2f(h.w));
    ((ushort4*)a.dh[z])[i] = h;
    ((ushort4*)a.dl[z])[i] = l;
}

// ---------------------------------------------------------------------------
// 4 weights [512][512] fp32 -> transposed hi/lo, one dispatch (z = weight).
struct WT4Args {
    const float* src[4];
    unsigned short* dh[4];
    unsigned short* dl[4];
};
__global__ __launch_bounds__(256)
void wtrans4(WT4Args a)
{
    __shared__ float T[32][33];
    const int z = blockIdx.z;
    const int Cc = 512, R = 512;
    const float* s = a.src[z];
    const int r0 = blockIdx.y * 32, c0 = blockIdx.x * 32;
    const int t = threadIdx.x;
    {
        const int r = t >> 3, cq = (t & 7) * 4;
        float4 v = *(const float4*)(s + (long)(r0 + r) * Cc + c0 + cq);
        T[r][cq] = v.x; T[r][cq + 1] = v.y; T[r][cq + 2] = v.z; T[r][cq + 3] = v.w;
    }
    __syncthreads();
    {
        const int c = t >> 3, rq = (t & 7) * 4;
        float x0 = T[rq][c], x1 = T[rq + 1][c], x2 = T[rq + 2][c], x3 = T[rq + 3][c];
        ushort4 h, l;
        h.x = f2bf(x0); l.x = f2bf(x0 - bf2f(h.x));
        h.y = f2bf(x1); l.y = f2bf(x1 - bf2f(h.y));
        h.z = f2bf(x2); l.z = f2bf(x2 - bf2f(h.z));
        h.w = f2bf(x3); l.w = f2bf(x3 - bf2f(h.w));
        long o = (long)(c0 + c) * R + r0 + rq;
        *(ushort4*)(a.dh[z] + o) = h;
        *(ushort4*)(a.dl[z] + o) = l;
    }
}

// ---------------------------------------------------------------------------
// Merged Q/K/V projection GEMM. grid (4, 64, 3); z selects {q,k,v}.
// C[8192,512] = A @ W^T + b. z<2: hi/lo out [M][C]. z==2: transposed hi/lo
// out VT[b][C][L] (per-batch), exploiting C/D layout's 4-consecutive-rows/lane.
struct ProjArgs {
    const unsigned short* Ah[3]; const unsigned short* Al[3];
    const unsigned short* Bh[3]; const unsigned short* Bl[3];
    const float* bias[3];
    unsigned short* Ch[3]; unsigned short* Cl[3];
};
__global__ __launch_bounds__(256)
void proj_gemm(ProjArgs pa)
{
    __shared__ __align__(16) unsigned short Ah[128][40], Al[128][40];
    __shared__ __align__(16) unsigned short Bh[128][40], Bl[128][40];

    const int z = blockIdx.z;
    const unsigned short* pAh = pa.Ah[z];
    const unsigned short* pAl = pa.Al[z];
    const unsigned short* pBh = pa.Bh[z];
    const unsigned short* pBl = pa.Bl[z];
    const float* bias = pa.bias[z];

    const int tid = threadIdx.x;
    const int m0 = blockIdx.y * 128, n0 = blockIdx.x * 128;
    const int w = tid >> 6, lane = tid & 63;
    const int wr = w >> 1, wc = w & 1;
    const int quad = lane >> 4, mr = lane & 15;

    f32x4 acc[4][4] = {};
    const int srow = tid >> 1, scol = (tid & 1) * 16;

    for (int k0 = 0; k0 < 512; k0 += 32) {
        const long ga = (long)(m0 + srow) * 512 + k0 + scol;
        const long gb = (long)(n0 + srow) * 512 + k0 + scol;
        bf16x8 vah0 = *(const bf16x8*)(pAh + ga);
        bf16x8 vah1 = *(const bf16x8*)(pAh + ga + 8);
        bf16x8 val0 = *(const bf16x8*)(pAl + ga);
        bf16x8 val1 = *(const bf16x8*)(pAl + ga + 8);
        bf16x8 vbh0 = *(const bf16x8*)(pBh + gb);
        bf16x8 vbh1 = *(const bf16x8*)(pBh + gb + 8);
        bf16x8 vbl0 = *(const bf16x8*)(pBl + gb);
        bf16x8 vbl1 = *(const bf16x8*)(pBl + gb + 8);
        *(bf16x8*)&Ah[srow][scol]     = vah0;
        *(bf16x8*)&Ah[srow][scol + 8] = vah1;
        *(bf16x8*)&Al[srow][scol]     = val0;
        *(bf16x8*)&Al[srow][scol + 8] = val1;
        *(bf16x8*)&Bh[srow][scol]     = vbh0;
        *(bf16x8*)&Bh[srow][scol + 8] = vbh1;
        *(bf16x8*)&Bl[srow][scol]     = vbl0;
        *(bf16x8*)&Bl[srow][scol + 8] = vbl1;
        __syncthreads();

        bf16x8 afh[4], afl[4], bfh[4], bfl[4];
        #pragma unroll
        for (int r = 0; r < 4; ++r) {
            const int ar = wr * 64 + r * 16 + mr;
            afh[r] = *(const bf16x8*)&Ah[ar][quad * 8];
            afl[r] = *(const bf16x8*)&Al[ar][quad * 8];
            const int br = wc * 64 + r * 16 + mr;
            bfh[r] = *(const bf16x8*)&Bh[br][quad * 8];
            bfl[r] = *(const bf16x8*)&Bl[br][quad * 8];
        }
        #pragma unroll
        for (int r = 0; r < 4; ++r)
            #pragma unroll
            for (int c = 0; c < 4; ++c) {
                acc[r][c] = __builtin_amdgcn_mfma_f32_16x16x32_bf16(afh[r], bfh[c], acc[r][c], 0, 0, 0);
                acc[r][c] = __builtin_amdgcn_mfma_f32_16x16x32_bf16(afh[r], bfl[c], acc[r][c], 0, 0, 0);
                acc[r][c] = __builtin_amdgcn_mfma_f32_16x16x32_bf16(afl[r], bfh[c], acc[r][c], 0, 0, 0);
            }
        __syncthreads();
    }

    if (z < 2) {
        unsigned short* Chi = pa.Ch[z];
        unsigned short* Clo = pa.Cl[z];
        #pragma unroll
        for (int r = 0; r < 4; ++r)
            #pragma unroll
            for (int c = 0; c < 4; ++c) {
                const int col = n0 + wc * 64 + c * 16 + mr;
                const float bv = bias[col];
                #pragma unroll
                for (int e = 0; e < 4; ++e) {
                    const int rowg = m0 + wr * 64 + r * 16 + quad * 4 + e;
                    const float v = acc[r][c][e] + bv;
                    const long off = (long)rowg * 512 + col;
                    const unsigned short h = f2bf(v);
                    Chi[off] = h;
                    Clo[off] = f2bf(v - bf2f(h));
                }
            }
    } else {
        // transposed: VT[b][col][l], l = rowg & 2047, b = rowg >> 11
        unsigned short* VTh = pa.Ch[2];
        unsigned short* VTl = pa.Cl[2];
        #pragma unroll
        for (int r = 0; r < 4; ++r)
            #pragma unroll
            for (int c = 0; c < 4; ++c) {
                const int col = n0 + wc * 64 + c * 16 + mr;
                const float bv = bias[col];
                const int rowg0 = m0 + wr * 64 + r * 16 + quad * 4;
                const int b = rowg0 >> 11, l0 = rowg0 & 2047;
                ushort4 hv, lv;
                float v;
                v = acc[r][c][0] + bv; hv.x = f2bf(v); lv.x = f2bf(v - bf2f(hv.x));
                v = acc[r][c][1] + bv; hv.y = f2bf(v); lv.y = f2bf(v - bf2f(hv.y));
                v = acc[r][c][2] + bv; hv.z = f2bf(v); lv.z = f2bf(v - bf2f(hv.z));
                v = acc[r][c][3] + bv; hv.w = f2bf(v); lv.w = f2bf(v - bf2f(hv.w));
                const long off = (long)b * (512 * 2048) + (long)col * 2048 + l0;
                *(ushort4*)(VTh + off) = hv;
                *(ushort4*)(VTl + off) = lv;
            }
    }
}

// ---------------------------------------------------------------------------
// Split-bf16 MFMA GEMM, NT, fp32 out. KSPLIT=1: z = batch. KSPLIT=2:
// z = batch*2 + ks; each half-K partial goes to Cf0 (ks=0) or Cf1 (ks=1).
template<int KSPLIT>
__global__ __launch_bounds__(256)
void gemm_nt(const unsigned short* __restrict__ Ah_g, const unsigned short* __restrict__ Al_g,
             const unsigned short* __restrict__ Bh_g, const unsigned short* __restrict__ Bl_g,
             float* __restrict__ Cf0, float* __restrict__ Cf1,
             int K, int lda, int ldb, int ldc, float alpha,
             long sA, long sB, long sC)
{
    __shared__ __align__(16) unsigned short Ah[128][40], Al[128][40];
    __shared__ __align__(16) unsigned short Bh[128][40], Bl[128][40];

    const int tid = threadIdx.x;
    const int m0 = blockIdx.y * 128, n0 = blockIdx.x * 128;
    const long zb = (KSPLIT == 2) ? (blockIdx.z >> 1) : blockIdx.z;
    const int ks = (KSPLIT == 2) ? (blockIdx.z & 1) : 0;
    const int kh = K / KSPLIT;
    const int k_begin = ks * kh, k_end = k_begin + kh;
    float* Cf = (ks == 0) ? Cf0 : Cf1;

    const unsigned short* pAh = Ah_g + zb * sA;
    const unsigned short* pAl = Al_g + zb * sA;
    const unsigned short* pBh = Bh_g + zb * sB;
    const unsigned short* pBl = Bl_g + zb * sB;

    const int w = tid >> 6, lane = tid & 63;
    const int wr = w >> 1, wc = w & 1;
    const int quad = lane >> 4, mr = lane & 15;

    f32x4 acc[4][4] = {};
    const int srow = tid >> 1, scol = (tid & 1) * 16;

    for (int k0 = k_begin; k0 < k_end; k0 += 32) {
        const long ga = (long)(m0 + srow) * lda + k0 + scol;
        const long gb = (long)(n0 + srow) * ldb + k0 + scol;
        bf16x8 vah0 = *(const bf16x8*)(pAh + ga);
        bf16x8 vah1 = *(const bf16x8*)(pAh + ga + 8);
        bf16x8 val0 = *(const bf16x8*)(pAl + ga);
        bf16x8 val1 = *(const bf16x8*)(pAl + ga + 8);
        bf16x8 vbh0 = *(const bf16x8*)(pBh + gb);
        bf16x8 vbh1 = *(const bf16x8*)(pBh + gb + 8);
        bf16x8 vbl0 = *(const bf16x8*)(pBl + gb);
        bf16x8 vbl1 = *(const bf16x8*)(pBl + gb + 8);
        *(bf16x8*)&Ah[srow][scol]     = vah0;
        *(bf16x8*)&Ah[srow][scol + 8] = vah1;
        *(bf16x8*)&Al[srow][scol]     = val0;
        *(bf16x8*)&Al[srow][scol + 8] = val1;
        *(bf16x8*)&Bh[srow][scol]     = vbh0;
        *(bf16x8*)&Bh[srow][scol + 8] = vbh1;
        *(bf16x8*)&Bl[srow][scol]     = vbl0;
        *(bf16x8*)&Bl[srow][scol + 8] = vbl1;
        __syncthreads();

        bf16x8 afh[4], afl[4], bfh[4], bfl[4];
        #pragma unroll
        for (int r = 0; r < 4; ++r) {
            const int ar = wr * 64 + r * 16 + mr;
            afh[r] = *(const bf16x8*)&Ah[ar][quad * 8];
            afl[r] = *(const bf16x8*)&Al[ar][quad * 8];
            const int br = wc * 64 + r * 16 + mr;
            bfh[r] = *(const bf16x8*)&Bh[br][quad * 8];
            bfl[r] = *(const bf16x8*)&Bl[br][quad * 8];
        }
        #pragma unroll
        for (int r = 0; r < 4; ++r)
            #pragma unroll
            for (int c = 0; c < 4; ++c) {
                acc[r][c] = __builtin_amdgcn_mfma_f32_16x16x32_bf16(afh[r], bfh[c], acc[r][c], 0, 0, 0);
                acc[r][c] = __builtin_amdgcn_mfma_f32_16x16x32_bf16(afh[r], bfl[c], acc[r][c], 0, 0, 0);
                acc[r][c] = __builtin_amdgcn_mfma_f32_16x16x32_bf16(afl[r], bfh[c], acc[r][c], 0, 0, 0);
            }
        __syncthreads();
    }

    #pragma unroll
    for (int r = 0; r < 4; ++r)
        #pragma unroll
        for (int c = 0; c < 4; ++c) {
            const int col = n0 + wc * 64 + c * 16 + mr;
            #pragma unroll
            for (int e = 0; e < 4; ++e) {
                const int rowg = m0 + wr * 64 + r * 16 + quad * 4 + e;
                Cf[zb * sC + (long)rowg * ldc + col] = acc[r][c][e] * alpha;
            }
        }
}

// ---------------------------------------------------------------------------
// Softmax over rows of 2048 fp32, writing P hi/lo IN PLACE.
__global__ __launch_bounds__(256)
void softmax_rows_hl(float* __restrict__ S)
{
    float* row = S + (long)blockIdx.x * 2048;
    const int tid = threadIdx.x;

    float4 v0 = *(float4*)(row + tid * 4);
    float4 v1 = *(float4*)(row + 1024 + tid * 4);
    float x[8] = { v0.x, v0.y, v0.z, v0.w, v1.x, v1.y, v1.z, v1.w };

    __shared__ float red[4];

    float lm = x[0];
    #pragma unroll
    for (int i = 1; i < 8; ++i) lm = fmaxf(lm, x[i]);
    #pragma unroll
    for (int off = 32; off > 0; off >>= 1) lm = fmaxf(lm, __shfl_down(lm, off));
    if ((tid & 63) == 0) red[tid >> 6] = lm;
    __syncthreads();
    if (tid == 0) red[0] = fmaxf(fmaxf(red[0], red[1]), fmaxf(red[2], red[3]));
    __syncthreads();
    const float rowmax = red[0];
    __syncthreads();

    float ls = 0.f;
    #pragma unroll
    for (int i = 0; i < 8; ++i) { x[i] = __expf(x[i] - rowmax); ls += x[i]; }
    #pragma unroll
    for (int off = 32; off > 0; off >>= 1) ls += __shfl_down(ls, off);
    if ((tid & 63) == 0) red[tid >> 6] = ls;
    __syncthreads();
    if (tid == 0) red[0] = red[0] + red[1] + red[2] + red[3];
    __syncthreads();
    const float inv = 1.0f / red[0];

    unsigned short* ph = (unsigned short*)row;
    unsigned short* pl = ph + 2048;
    ushort4 h0, l0, h1, l1;
    float y;
    y = x[0] * inv; h0.x = f2bf(y); l0.x = f2bf(y - bf2f(h0.x));
    y = x[1] * inv; h0.y = f2bf(y); l0.y = f2bf(y - bf2f(h0.y));
    y = x[2] * inv; h0.z = f2bf(y); l0.z = f2bf(y - bf2f(h0.z));
    y = x[3] * inv; h0.w = f2bf(y); l0.w = f2bf(y - bf2f(h0.w));
    y = x[4] * inv; h1.x = f2bf(y); l1.x = f2bf(y - bf2f(h1.x));
    y = x[5] * inv; h1.y = f2bf(y); l1.y = f2bf(y - bf2f(h1.y));
    y = x[6] * inv; h1.z = f2bf(y); l1.z = f2bf(y - bf2f(h1.z));
    y = x[7] * inv; h1.w = f2bf(y); l1.w = f2bf(y - bf2f(h1.w));
    *(ushort4*)(ph + tid * 4) = h0;
    *(ushort4*)(ph + 1024 + tid * 4) = h1;
    *(ushort4*)(pl + tid * 4) = l0;
    *(ushort4*)(pl + 1024 + tid * 4) = l1;
}

// ---------------------------------------------------------------------------
// O = p0 + p1 -> hi/lo split
__global__ __launch_bounds__(256)
void reduce_hl(const float* __restrict__ p0, const float* __restrict__ p1,
               unsigned short* __restrict__ oh, unsigned short* __restrict__ ol)
{
    long i = (long)blockIdx.x * 256 + threadIdx.x;
    float4 a = ((const float4*)p0)[i];
    float4 b = ((const float4*)p1)[i];
    float4 v = make_float4(a.x + b.x, a.y + b.y, a.z + b.z, a.w + b.w);
    ushort4 h, l;
    h.x = f2bf(v.x); l.x = f2bf(v.x - bf2f(h.x));
    h.y = f2bf(v.y); l.y = f2bf(v.y - bf2f(h.y));
    h.z = f2bf(v.z); l.z = f2bf(v.z - bf2f(h.z));
    h.w = f2bf(v.w); l.w = f2bf(v.w - bf2f(h.w));
    ((ushort4*)oh)[i] = h;
    ((ushort4*)ol)[i] = l;
}

// out = p0 + p1 + bias (row length 512 floats = 128 float4)
__global__ __launch_bounds__(256)
void reduce_bias_f32(const float* __restrict__ p0, const float* __restrict__ p1,
                     const float* __restrict__ bias, float* __restrict__ out)
{
    long i = (long)blockIdx.x * 256 + threadIdx.x;
    float4 a = ((const float4*)p0)[i];
    float4 b = ((const float4*)p1)[i];
    float4 bb = ((const float4*)bias)[i & 127];
    ((float4*)out)[i] = make_float4(a.x + b.x + bb.x, a.y + b.y + bb.y,
                                    a.z + b.z + bb.z, a.w + b.w + bb.w);
}

// ---------------------------------------------------------------------------
extern "C" void kernel_launch(void* const* d_in, const int* in_sizes, int n_in,
                              void* d_out, int out_size, void* d_ws, size_t ws_size,
                              hipStream_t stream) {
    const float* query = (const float*)d_in[0];
    const float* key   = (const float*)d_in[1];
    const float* value = (const float*)d_in[2];
    const float* Wq    = (const float*)d_in[3];
    const float* bq    = (const float*)d_in[4];
    const float* Wk    = (const float*)d_in[5];
    const float* bk    = (const float*)d_in[6];
    const float* Wv    = (const float*)d_in[7];
    const float* bv    = (const float*)d_in[8];
    const float* Wo    = (const float*)d_in[9];
    const float* bo    = (const float*)d_in[10];
    float* out = (float*)d_out;

    const int B = 4, L = 2048, C = 512;
    const int M = B * L;               // 8192
    char* ws = (char*)d_ws;

    // ---- workspace map (bytes), total 121,634,816 (same max as R2) --------
    // [0, 4.19M):        WT hi/lo x4
    // [4.19M, 54.5M):    in_q/in_k/in_v hi/lo  (dead after projections)
    // [4.19M, 71.3M):    S fp32 67 MB (written by QK^T, overlays inputs);
    //                    after PV, first 33.5 MB host final-proj partials
    // [71.3M, 88.1M):    VT hi/lo
    // [88.1M, 104.9M):   Q hi/lo  -> O hi/lo after reduce
    // [104.9M, 121.6M):  K hi/lo  -> PV partial-1 fp32 after QK^T
    // PV partial-0 -> d_out (scratch, overwritten by final reduce)
    unsigned short* WqT_h = (unsigned short*)(ws);
    unsigned short* WqT_l = (unsigned short*)(ws + 524288);
    unsigned short* WkT_h = (unsigned short*)(ws + 1048576);
    unsigned short* WkT_l = (unsigned short*)(ws + 1572864);
    unsigned short* WvT_h = (unsigned short*)(ws + 2097152);
    unsigned short* WvT_l = (unsigned short*)(ws + 2621440);
    unsigned short* WoT_h = (unsigned short*)(ws + 3145728);
    unsigned short* WoT_l = (unsigned short*)(ws + 3670016);
    unsigned short* inq_h = (unsigned short*)(ws + 4194304);
    unsigned short* inq_l = (unsigned short*)(ws + 12582912);
    unsigned short* ink_h = (unsigned short*)(ws + 20971520);
    unsigned short* ink_l = (unsigned short*)(ws + 29360128);
    unsigned short* inv_h = (unsigned short*)(ws + 37748736);
    unsigned short* inv_l = (unsigned short*)(ws + 46137344);
    float*          S     = (float*)(ws + 4194304);
    float*          Fp0   = (float*)(ws + 4194304);
    float*          Fp1   = (float*)(ws + 20971520);
    unsigned short* VT_h  = (unsigned short*)(ws + 71303168);
    unsigned short* VT_l  = (unsigned short*)(ws + 79691776);
    unsigned short* Q_h   = (unsigned short*)(ws + 88080384);
    unsigned short* Q_l   = (unsigned short*)(ws + 96468992);
    unsigned short* K_h   = (unsigned short*)(ws + 104857600);
    unsigned short* K_l   = (unsigned short*)(ws + 113246208);
    unsigned short* O_h   = Q_h;
    unsigned short* O_l   = Q_l;
    float*          Opart1 = (float*)(ws + 104857600);

    const dim3 blk(256);
    const float scale = 1.0f / sqrtf((float)C);
    const long LC = (long)L * C;      // 1,048,576
    const long LL = (long)L * L;      // 4,194,304

    // 1) weight transposes (one dispatch)
    WT4Args wt;
    wt.src[0] = Wq; wt.src[1] = Wk; wt.src[2] = Wv; wt.src[3] = Wo;
    wt.dh[0] = WqT_h; wt.dh[1] = WkT_h; wt.dh[2] = WvT_h; wt.dh[3] = WoT_h;
    wt.dl[0] = WqT_l; wt.dl[1] = WkT_l; wt.dl[2] = WvT_l; wt.dl[3] = WoT_l;
    wtrans4<<<dim3(16, 16, 4), blk, 0, stream>>>(wt);

    // 2) input splits (one dispatch)
    const long n4 = (long)M * C / 4;   // 1,048,576
    Split3Args sp;
    sp.src[0] = query; sp.src[1] = key; sp.src[2] = value;
    sp.dh[0] = inq_h; sp.dh[1] = ink_h; sp.dh[2] = inv_h;
    sp.dl[0] = inq_l; sp.dl[1] = ink_l; sp.dl[2] = inv_l;
    split_rows3<<<dim3((unsigned)((n4 + 255) / 256), 1, 3), blk, 0, stream>>>(sp, n4);

    // 3) merged projections: Q, K -> hi/lo [M][C]; V -> transposed VT[b][C][L]
    ProjArgs pa;
    pa.Ah[0] = inq_h; pa.Al[0] = inq_l; pa.Bh[0] = WqT_h; pa.Bl[0] = WqT_l;
    pa.bias[0] = bq;  pa.Ch[0] = Q_h;   pa.Cl[0] = Q_l;
    pa.Ah[1] = ink_h; pa.Al[1] = ink_l; pa.Bh[1] = WkT_h; pa.Bl[1] = WkT_l;
    pa.bias[1] = bk;  pa.Ch[1] = K_h;   pa.Cl[1] = K_l;
    pa.Ah[2] = inv_h; pa.Al[2] = inv_l; pa.Bh[2] = WvT_h; pa.Bl[2] = WvT_l;
    pa.bias[2] = bv;  pa.Ch[2] = VT_h;  pa.Cl[2] = VT_l;
    proj_gemm<<<dim3(4, 64, 3), blk, 0, stream>>>(pa);

    // 4) S = scale * Q @ K^T (per batch), fp32 (overlays dead inputs)
    gemm_nt<1><<<dim3(16, 16, 4), blk, 0, stream>>>(Q_h, Q_l, K_h, K_l,
        S, nullptr, C, C, C, L, scale, LC, LC, LL);

    // 5) softmax -> P hi/lo in place
    softmax_rows_hl<<<dim3(M), blk, 0, stream>>>(S);

    // 6) PV split-K2: partials to d_out (ks=0) and dead-K region (ks=1)
    gemm_nt<2><<<dim3(4, 16, 8), blk, 0, stream>>>(
        (unsigned short*)S, (unsigned short*)S + 2048, VT_h, VT_l,
        out, Opart1, L, 4096, L, C, 1.0f, (long)L * 4096, LC, LC);

    // 7) O = partial0 + partial1 -> hi/lo over dead Q
    reduce_hl<<<dim3((unsigned)(n4 / 256)), blk, 0, stream>>>(out, Opart1, O_h, O_l);

    // 8) final projection split-K2: partials into dead S region
    gemm_nt<2><<<dim3(4, 64, 2), blk, 0, stream>>>(O_h, O_l, WoT_h, WoT_l,
        Fp0, Fp1, C, C, C, C, 1.0f, 0, 0, 0);

    // 9) out = Fp0 + Fp1 + bo
    reduce_bias_f32<<<dim3((unsigned)(n4 / 256)), blk, 0, stream>>>(Fp0, Fp1, bo, out);
}

// Round 5
// 348.023 us; speedup vs baseline: 3.4406x; 1.0602x over previous
//
#include <hip/hip_runtime.h>
#include <math.h>

typedef __attribute__((ext_vector_type(8))) short bf16x8;
typedef __attribute__((ext_vector_type(4))) float f32x4;

__device__ __forceinline__ unsigned short f2bf(float x) {
    union { float f; unsigned u; } v; v.f = x;
    unsigned r = v.u + 0x7FFFu + ((v.u >> 16) & 1u);   // RNE
    return (unsigned short)(r >> 16);
}
__device__ __forceinline__ float bf2f(unsigned short h) {
    union { float f; unsigned u; } v; v.u = ((unsigned)h) << 16; return v.f;
}

// XCD-aware tile decode: id -> (m, n, zz). Blocks sharing an A-tile (same
// m-group) land on the SAME XCD (id%8) and are adjacent in schedule order,
// so the shared operand comes from that XCD's L2 instead of HBM x4.
// ML = MT*ZT/8 (m-groups per XCD). M_INNER: m varies fastest within an XCD
// (for shapes where B is the small cacheable operand).
template<bool M_INNER>
__device__ __forceinline__ void tile_decode(int id, int NT, int MT, int ML,
                                            int& m, int& n, int& zz)
{
    const int xcd = id & 7;
    const int s = id >> 3;
    int mloc;
    if (M_INNER) { mloc = s % ML; n = s / ML; }
    else         { n = s % NT;   mloc = s / NT; }
    const int g = xcd * ML + mloc;
    m = g % MT;
    zz = g / MT;
}

// ---------------------------------------------------------------------------
// 3 input tensors -> hi/lo split, one dispatch (grid.z selects tensor).
struct Split3Args {
    const float* src[3];
    unsigned short* dh[3];
    unsigned short* dl[3];
};
__global__ __launch_bounds__(256)
void split_rows3(Split3Args a, long n4)
{
    const int z = blockIdx.z;
    long i = (long)blockIdx.x * 256 + threadIdx.x;
    if (i >= n4) return;
    float4 v = ((const float4*)a.src[z])[i];
    ushort4 h, l;
    h.x = f2bf(v.x); l.x = f2bf(v.x - bf2f(h.x));
    h.y = f2bf(v.y); l.y = f2bf(v.y - bf2f(h.y));
    h.z = f2bf(v.z); l.z = f2bf(v.z - bf2f(h.z));
    h.w = f2bf(v.w); l.w = f2bf(v.w - bf2f(h.w));
    ((ushort4*)a.dh[z])[i] = h;
    ((ushort4*)a.dl[z])[i] = l;
}

// ---------------------------------------------------------------------------
// 4 weights [512][512] fp32 -> transposed hi/lo, one dispatch (z = weight).
struct WT4Args {
    const float* src[4];
    unsigned short* dh[4];
    unsigned short* dl[4];
};
__global__ __launch_bounds__(256)
void wtrans4(WT4Args a)
{
    __shared__ float T[32][33];
    const int z = blockIdx.z;
    const int Cc = 512, R = 512;
    const float* s = a.src[z];
    const int r0 = blockIdx.y * 32, c0 = blockIdx.x * 32;
    const int t = threadIdx.x;
    {
        const int r = t >> 3, cq = (t & 7) * 4;
        float4 v = *(const float4*)(s + (long)(r0 + r) * Cc + c0 + cq);
        T[r][cq] = v.x; T[r][cq + 1] = v.y; T[r][cq + 2] = v.z; T[r][cq + 3] = v.w;
    }
    __syncthreads();
    {
        const int c = t >> 3, rq = (t & 7) * 4;
        float x0 = T[rq][c], x1 = T[rq + 1][c], x2 = T[rq + 2][c], x3 = T[rq + 3][c];
        ushort4 h, l;
        h.x = f2bf(x0); l.x = f2bf(x0 - bf2f(h.x));
        h.y = f2bf(x1); l.y = f2bf(x1 - bf2f(h.y));
        h.z = f2bf(x2); l.z = f2bf(x2 - bf2f(h.z));
        h.w = f2bf(x3); l.w = f2bf(x3 - bf2f(h.w));
        long o = (long)(c0 + c) * R + r0 + rq;
        *(ushort4*)(a.dh[z] + o) = h;
        *(ushort4*)(a.dl[z] + o) = l;
    }
}

// ---------------------------------------------------------------------------
// Merged Q/K/V projection GEMM. 1-D grid 768 blocks; decode NT=4, MT=64,
// ZT=3 (z = which projection), ML=24, n-inner.
struct ProjArgs {
    const unsigned short* Ah[3]; const unsigned short* Al[3];
    const unsigned short* Bh[3]; const unsigned short* Bl[3];
    const float* bias[3];
    unsigned short* Ch[3]; unsigned short* Cl[3];
};
__global__ __launch_bounds__(256)
void proj_gemm(ProjArgs pa)
{
    __shared__ __align__(16) unsigned short Ah[128][40], Al[128][40];
    __shared__ __align__(16) unsigned short Bh[128][40], Bl[128][40];

    int mt, nt, z;
    tile_decode<false>(blockIdx.x, 4, 64, 24, mt, nt, z);

    const unsigned short* pAh = pa.Ah[z];
    const unsigned short* pAl = pa.Al[z];
    const unsigned short* pBh = pa.Bh[z];
    const unsigned short* pBl = pa.Bl[z];
    const float* bias = pa.bias[z];

    const int tid = threadIdx.x;
    const int m0 = mt * 128, n0 = nt * 128;
    const int w = tid >> 6, lane = tid & 63;
    const int wr = w >> 1, wc = w & 1;
    const int quad = lane >> 4, mr = lane & 15;

    f32x4 acc[4][4] = {};
    const int srow = tid >> 1, scol = (tid & 1) * 16;

    for (int k0 = 0; k0 < 512; k0 += 32) {
        const long ga = (long)(m0 + srow) * 512 + k0 + scol;
        const long gb = (long)(n0 + srow) * 512 + k0 + scol;
        bf16x8 vah0 = *(const bf16x8*)(pAh + ga);
        bf16x8 vah1 = *(const bf16x8*)(pAh + ga + 8);
        bf16x8 val0 = *(const bf16x8*)(pAl + ga);
        bf16x8 val1 = *(const bf16x8*)(pAl + ga + 8);
        bf16x8 vbh0 = *(const bf16x8*)(pBh + gb);
        bf16x8 vbh1 = *(const bf16x8*)(pBh + gb + 8);
        bf16x8 vbl0 = *(const bf16x8*)(pBl + gb);
        bf16x8 vbl1 = *(const bf16x8*)(pBl + gb + 8);
        *(bf16x8*)&Ah[srow][scol]     = vah0;
        *(bf16x8*)&Ah[srow][scol + 8] = vah1;
        *(bf16x8*)&Al[srow][scol]     = val0;
        *(bf16x8*)&Al[srow][scol + 8] = val1;
        *(bf16x8*)&Bh[srow][scol]     = vbh0;
        *(bf16x8*)&Bh[srow][scol + 8] = vbh1;
        *(bf16x8*)&Bl[srow][scol]     = vbl0;
        *(bf16x8*)&Bl[srow][scol + 8] = vbl1;
        __syncthreads();

        bf16x8 afh[4], afl[4], bfh[4], bfl[4];
        #pragma unroll
        for (int r = 0; r < 4; ++r) {
            const int ar = wr * 64 + r * 16 + mr;
            afh[r] = *(const bf16x8*)&Ah[ar][quad * 8];
            afl[r] = *(const bf16x8*)&Al[ar][quad * 8];
            const int br = wc * 64 + r * 16 + mr;
            bfh[r] = *(const bf16x8*)&Bh[br][quad * 8];
            bfl[r] = *(const bf16x8*)&Bl[br][quad * 8];
        }
        #pragma unroll
        for (int r = 0; r < 4; ++r)
            #pragma unroll
            for (int c = 0; c < 4; ++c) {
                acc[r][c] = __builtin_amdgcn_mfma_f32_16x16x32_bf16(afh[r], bfh[c], acc[r][c], 0, 0, 0);
                acc[r][c] = __builtin_amdgcn_mfma_f32_16x16x32_bf16(afh[r], bfl[c], acc[r][c], 0, 0, 0);
                acc[r][c] = __builtin_amdgcn_mfma_f32_16x16x32_bf16(afl[r], bfh[c], acc[r][c], 0, 0, 0);
            }
        __syncthreads();
    }

    if (z < 2) {
        unsigned short* Chi = pa.Ch[z];
        unsigned short* Clo = pa.Cl[z];
        #pragma unroll
        for (int r = 0; r < 4; ++r)
            #pragma unroll
            for (int c = 0; c < 4; ++c) {
                const int col = n0 + wc * 64 + c * 16 + mr;
                const float bv = bias[col];
                #pragma unroll
                for (int e = 0; e < 4; ++e) {
                    const int rowg = m0 + wr * 64 + r * 16 + quad * 4 + e;
                    const float v = acc[r][c][e] + bv;
                    const long off = (long)rowg * 512 + col;
                    const unsigned short h = f2bf(v);
                    Chi[off] = h;
                    Clo[off] = f2bf(v - bf2f(h));
                }
            }
    } else {
        // transposed: VT[b][col][l], l = rowg & 2047, b = rowg >> 11
        unsigned short* VTh = pa.Ch[2];
        unsigned short* VTl = pa.Cl[2];
        #pragma unroll
        for (int r = 0; r < 4; ++r)
            #pragma unroll
            for (int c = 0; c < 4; ++c) {
                const int col = n0 + wc * 64 + c * 16 + mr;
                const float bv = bias[col];
                const int rowg0 = m0 + wr * 64 + r * 16 + quad * 4;
                const int b = rowg0 >> 11, l0 = rowg0 & 2047;
                ushort4 hv, lv;
                float v;
                v = acc[r][c][0] + bv; hv.x = f2bf(v); lv.x = f2bf(v - bf2f(hv.x));
                v = acc[r][c][1] + bv; hv.y = f2bf(v); lv.y = f2bf(v - bf2f(hv.y));
                v = acc[r][c][2] + bv; hv.z = f2bf(v); lv.z = f2bf(v - bf2f(hv.z));
                v = acc[r][c][3] + bv; hv.w = f2bf(v); lv.w = f2bf(v - bf2f(hv.w));
                const long off = (long)b * (512 * 2048) + (long)col * 2048 + l0;
                *(ushort4*)(VTh + off) = hv;
                *(ushort4*)(VTl + off) = lv;
            }
    }
}

// ---------------------------------------------------------------------------
// Split-bf16 MFMA GEMM, NT, fp32 out. 1-D grid with XCD decode.
// KSPLIT=2: zz = batch*2 + ks; partial -> Cf0 (ks=0) / Cf1 (ks=1).
template<int KSPLIT, bool M_INNER>
__global__ __launch_bounds__(256)
void gemm_nt(const unsigned short* __restrict__ Ah_g, const unsigned short* __restrict__ Al_g,
             const unsigned short* __restrict__ Bh_g, const unsigned short* __restrict__ Bl_g,
             float* __restrict__ Cf0, float* __restrict__ Cf1,
             int NT, int MT, int ML,
             int K, int lda, int ldb, int ldc, float alpha,
             long sA, long sB, long sC)
{
    __shared__ __align__(16) unsigned short Ah[128][40], Al[128][40];
    __shared__ __align__(16) unsigned short Bh[128][40], Bl[128][40];

    int mt, nt, zz;
    tile_decode<M_INNER>(blockIdx.x, NT, MT, ML, mt, nt, zz);

    const int tid = threadIdx.x;
    const int m0 = mt * 128, n0 = nt * 128;
    const long zb = (KSPLIT == 2) ? (zz >> 1) : zz;
    const int ks = (KSPLIT == 2) ? (zz & 1) : 0;
    const int kh = K / KSPLIT;
    const int k_begin = ks * kh, k_end = k_begin + kh;
    float* Cf = (ks == 0) ? Cf0 : Cf1;

    const unsigned short* pAh = Ah_g + zb * sA;
    const unsigned short* pAl = Al_g + zb * sA;
    const unsigned short* pBh = Bh_g + zb * sB;
    const unsigned short* pBl = Bl_g + zb * sB;

    const int w = tid >> 6, lane = tid & 63;
    const int wr = w >> 1, wc = w & 1;
    const int quad = lane >> 4, mr = lane & 15;

    f32x4 acc[4][4] = {};
    const int srow = tid >> 1, scol = (tid & 1) * 16;

    for (int k0 = k_begin; k0 < k_end; k0 += 32) {
        const long ga = (long)(m0 + srow) * lda + k0 + scol;
        const long gb = (long)(n0 + srow) * ldb + k0 + scol;
        bf16x8 vah0 = *(const bf16x8*)(pAh + ga);
        bf16x8 vah1 = *(const bf16x8*)(pAh + ga + 8);
        bf16x8 val0 = *(const bf16x8*)(pAl + ga);
        bf16x8 val1 = *(const bf16x8*)(pAl + ga + 8);
        bf16x8 vbh0 = *(const bf16x8*)(pBh + gb);
        bf16x8 vbh1 = *(const bf16x8*)(pBh + gb + 8);
        bf16x8 vbl0 = *(const bf16x8*)(pBl + gb);
        bf16x8 vbl1 = *(const bf16x8*)(pBl + gb + 8);
        *(bf16x8*)&Ah[srow][scol]     = vah0;
        *(bf16x8*)&Ah[srow][scol + 8] = vah1;
        *(bf16x8*)&Al[srow][scol]     = val0;
        *(bf16x8*)&Al[srow][scol + 8] = val1;
        *(bf16x8*)&Bh[srow][scol]     = vbh0;
        *(bf16x8*)&Bh[srow][scol + 8] = vbh1;
        *(bf16x8*)&Bl[srow][scol]     = vbl0;
        *(bf16x8*)&Bl[srow][scol + 8] = vbl1;
        __syncthreads();

        bf16x8 afh[4], afl[4], bfh[4], bfl[4];
        #pragma unroll
        for (int r = 0; r < 4; ++r) {
            const int ar = wr * 64 + r * 16 + mr;
            afh[r] = *(const bf16x8*)&Ah[ar][quad * 8];
            afl[r] = *(const bf16x8*)&Al[ar][quad * 8];
            const int br = wc * 64 + r * 16 + mr;
            bfh[r] = *(const bf16x8*)&Bh[br][quad * 8];
            bfl[r] = *(const bf16x8*)&Bl[br][quad * 8];
        }
        #pragma unroll
        for (int r = 0; r < 4; ++r)
            #pragma unroll
            for (int c = 0; c < 4; ++c) {
                acc[r][c] = __builtin_amdgcn_mfma_f32_16x16x32_bf16(afh[r], bfh[c], acc[r][c], 0, 0, 0);
                acc[r][c] = __builtin_amdgcn_mfma_f32_16x16x32_bf16(afh[r], bfl[c], acc[r][c], 0, 0, 0);
                acc[r][c] = __builtin_amdgcn_mfma_f32_16x16x32_bf16(afl[r], bfh[c], acc[r][c], 0, 0, 0);
            }
        __syncthreads();
    }

    #pragma unroll
    for (int r = 0; r < 4; ++r)
        #pragma unroll
        for (int c = 0; c < 4; ++c) {
            const int col = n0 + wc * 64 + c * 16 + mr;
            #pragma unroll
            for (int e = 0; e < 4; ++e) {
                const int rowg = m0 + wr * 64 + r * 16 + quad * 4 + e;
                Cf[zb * sC + (long)rowg * ldc + col] = acc[r][c][e] * alpha;
            }
        }
}

// ---------------------------------------------------------------------------
// Softmax over rows of 2048 fp32, writing P hi/lo IN PLACE.
__global__ __launch_bounds__(256)
void softmax_rows_hl(float* __restrict__ S)
{
    float* row = S + (long)blockIdx.x * 2048;
    const int tid = threadIdx.x;

    float4 v0 = *(float4*)(row + tid * 4);
    float4 v1 = *(float4*)(row + 1024 + tid * 4);
    float x[8] = { v0.x, v0.y, v0.z, v0.w, v1.x, v1.y, v1.z, v1.w };

    __shared__ float red[4];

    float lm = x[0];
    #pragma unroll
    for (int i = 1; i < 8; ++i) lm = fmaxf(lm, x[i]);
    #pragma unroll
    for (int off = 32; off > 0; off >>= 1) lm = fmaxf(lm, __shfl_down(lm, off));
    if ((tid & 63) == 0) red[tid >> 6] = lm;
    __syncthreads();
    if (tid == 0) red[0] = fmaxf(fmaxf(red[0], red[1]), fmaxf(red[2], red[3]));
    __syncthreads();
    const float rowmax = red[0];
    __syncthreads();

    float ls = 0.f;
    #pragma unroll
    for (int i = 0; i < 8; ++i) { x[i] = __expf(x[i] - rowmax); ls += x[i]; }
    #pragma unroll
    for (int off = 32; off > 0; off >>= 1) ls += __shfl_down(ls, off);
    if ((tid & 63) == 0) red[tid >> 6] = ls;
    __syncthreads();
    if (tid == 0) red[0] = red[0] + red[1] + red[2] + red[3];
    __syncthreads();
    const float inv = 1.0f / red[0];

    unsigned short* ph = (unsigned short*)row;
    unsigned short* pl = ph + 2048;
    ushort4 h0, l0, h1, l1;
    float y;
    y = x[0] * inv; h0.x = f2bf(y); l0.x = f2bf(y - bf2f(h0.x));
    y = x[1] * inv; h0.y = f2bf(y); l0.y = f2bf(y - bf2f(h0.y));
    y = x[2] * inv; h0.z = f2bf(y); l0.z = f2bf(y - bf2f(h0.z));
    y = x[3] * inv; h0.w = f2bf(y); l0.w = f2bf(y - bf2f(h0.w));
    y = x[4] * inv; h1.x = f2bf(y); l1.x = f2bf(y - bf2f(h1.x));
    y = x[5] * inv; h1.y = f2bf(y); l1.y = f2bf(y - bf2f(h1.y));
    y = x[6] * inv; h1.z = f2bf(y); l1.z = f2bf(y - bf2f(h1.z));
    y = x[7] * inv; h1.w = f2bf(y); l1.w = f2bf(y - bf2f(h1.w));
    *(ushort4*)(ph + tid * 4) = h0;
    *(ushort4*)(ph + 1024 + tid * 4) = h1;
    *(ushort4*)(pl + tid * 4) = l0;
    *(ushort4*)(pl + 1024 + tid * 4) = l1;
}

// ---------------------------------------------------------------------------
// O = p0 + p1 -> hi/lo split
__global__ __launch_bounds__(256)
void reduce_hl(const float* __restrict__ p0, const float* __restrict__ p1,
               unsigned short* __restrict__ oh, unsigned short* __restrict__ ol)
{
    long i = (long)blockIdx.x * 256 + threadIdx.x;
    float4 a = ((const float4*)p0)[i];
    float4 b = ((const float4*)p1)[i];
    float4 v = make_float4(a.x + b.x, a.y + b.y, a.z + b.z, a.w + b.w);
    ushort4 h, l;
    h.x = f2bf(v.x); l.x = f2bf(v.x - bf2f(h.x));
    h.y = f2bf(v.y); l.y = f2bf(v.y - bf2f(h.y));
    h.z = f2bf(v.z); l.z = f2bf(v.z - bf2f(h.z));
    h.w = f2bf(v.w); l.w = f2bf(v.w - bf2f(h.w));
    ((ushort4*)oh)[i] = h;
    ((ushort4*)ol)[i] = l;
}

// out = p0 + p1 + bias (row length 512 floats = 128 float4)
__global__ __launch_bounds__(256)
void reduce_bias_f32(const float* __restrict__ p0, const float* __restrict__ p1,
                     const float* __restrict__ bias, float* __restrict__ out)
{
    long i = (long)blockIdx.x * 256 + threadIdx.x;
    float4 a = ((const float4*)p0)[i];
    float4 b = ((const float4*)p1)[i];
    float4 bb = ((const float4*)bias)[i & 127];
    ((float4*)out)[i] = make_float4(a.x + b.x + bb.x, a.y + b.y + bb.y,
                                    a.z + b.z + bb.z, a.w + b.w + bb.w);
}

// ---------------------------------------------------------------------------
extern "C" void kernel_launch(void* const* d_in, const int* in_sizes, int n_in,
                              void* d_out, int out_size, void* d_ws, size_t ws_size,
                              hipStream_t stream) {
    const float* query = (const float*)d_in[0];
    const float* key   = (const float*)d_in[1];
    const float* value = (const float*)d_in[2];
    const float* Wq    = (const float*)d_in[3];
    const float* bq    = (const float*)d_in[4];
    const float* Wk    = (const float*)d_in[5];
    const float* bk    = (const float*)d_in[6];
    const float* Wv    = (const float*)d_in[7];
    const float* bv    = (const float*)d_in[8];
    const float* Wo    = (const float*)d_in[9];
    const float* bo    = (const float*)d_in[10];
    float* out = (float*)d_out;

    const int B = 4, L = 2048, C = 512;
    const int M = B * L;               // 8192
    char* ws = (char*)d_ws;

    // ---- workspace map (bytes), total 121,634,816 (same as R3) ------------
    unsigned short* WqT_h = (unsigned short*)(ws);
    unsigned short* WqT_l = (unsigned short*)(ws + 524288);
    unsigned short* WkT_h = (unsigned short*)(ws + 1048576);
    unsigned short* WkT_l = (unsigned short*)(ws + 1572864);
    unsigned short* WvT_h = (unsigned short*)(ws + 2097152);
    unsigned short* WvT_l = (unsigned short*)(ws + 2621440);
    unsigned short* WoT_h = (unsigned short*)(ws + 3145728);
    unsigned short* WoT_l = (unsigned short*)(ws + 3670016);
    unsigned short* inq_h = (unsigned short*)(ws + 4194304);
    unsigned short* inq_l = (unsigned short*)(ws + 12582912);
    unsigned short* ink_h = (unsigned short*)(ws + 20971520);
    unsigned short* ink_l = (unsigned short*)(ws + 29360128);
    unsigned short* inv_h = (unsigned short*)(ws + 37748736);
    unsigned short* inv_l = (unsigned short*)(ws + 46137344);
    float*          S     = (float*)(ws + 4194304);
    float*          Fp0   = (float*)(ws + 4194304);
    float*          Fp1   = (float*)(ws + 20971520);
    unsigned short* VT_h  = (unsigned short*)(ws + 71303168);
    unsigned short* VT_l  = (unsigned short*)(ws + 79691776);
    unsigned short* Q_h   = (unsigned short*)(ws + 88080384);
    unsigned short* Q_l   = (unsigned short*)(ws + 96468992);
    unsigned short* K_h   = (unsigned short*)(ws + 104857600);
    unsigned short* K_l   = (unsigned short*)(ws + 113246208);
    unsigned short* O_h   = Q_h;
    unsigned short* O_l   = Q_l;
    float*          Opart1 = (float*)(ws + 104857600);

    const dim3 blk(256);
    const float scale = 1.0f / sqrtf((float)C);
    const long LC = (long)L * C;      // 1,048,576
    const long LL = (long)L * L;      // 4,194,304

    // 1) weight transposes (one dispatch)
    WT4Args wt;
    wt.src[0] = Wq; wt.src[1] = Wk; wt.src[2] = Wv; wt.src[3] = Wo;
    wt.dh[0] = WqT_h; wt.dh[1] = WkT_h; wt.dh[2] = WvT_h; wt.dh[3] = WoT_h;
    wt.dl[0] = WqT_l; wt.dl[1] = WkT_l; wt.dl[2] = WvT_l; wt.dl[3] = WoT_l;
    wtrans4<<<dim3(16, 16, 4), blk, 0, stream>>>(wt);

    // 2) input splits (one dispatch)
    const long n4 = (long)M * C / 4;   // 1,048,576
    Split3Args sp;
    sp.src[0] = query; sp.src[1] = key; sp.src[2] = value;
    sp.dh[0] = inq_h; sp.dh[1] = ink_h; sp.dh[2] = inv_h;
    sp.dl[0] = inq_l; sp.dl[1] = ink_l; sp.dl[2] = inv_l;
    split_rows3<<<dim3((unsigned)((n4 + 255) / 256), 1, 3), blk, 0, stream>>>(sp, n4);

    // 3) merged projections (768 blocks, XCD-decoded: NT=4, MT=64, ML=24)
    ProjArgs pa;
    pa.Ah[0] = inq_h; pa.Al[0] = inq_l; pa.Bh[0] = WqT_h; pa.Bl[0] = WqT_l;
    pa.bias[0] = bq;  pa.Ch[0] = Q_h;   pa.Cl[0] = Q_l;
    pa.Ah[1] = ink_h; pa.Al[1] = ink_l; pa.Bh[1] = WkT_h; pa.Bl[1] = WkT_l;
    pa.bias[1] = bk;  pa.Ch[1] = K_h;   pa.Cl[1] = K_l;
    pa.Ah[2] = inv_h; pa.Al[2] = inv_l; pa.Bh[2] = WvT_h; pa.Bl[2] = WvT_l;
    pa.bias[2] = bv;  pa.Ch[2] = VT_h;  pa.Cl[2] = VT_l;
    proj_gemm<<<dim3(768), blk, 0, stream>>>(pa);

    // 4) S = scale * Q @ K^T. 1024 blocks; m-inner (B half fits L2):
    //    NT=16, MT=16, ZT=4, ML=8
    gemm_nt<1, true><<<dim3(1024), blk, 0, stream>>>(Q_h, Q_l, K_h, K_l,
        S, nullptr, 16, 16, 8, C, C, C, L, scale, LC, LC, LL);

    // 5) softmax -> P hi/lo in place
    softmax_rows_hl<<<dim3(M), blk, 0, stream>>>(S);

    // 6) PV split-K2: 512 blocks; n-inner. NT=4, MT=16, ZT=8, ML=16.
    //    Each XCD owns exactly one (batch, k-half): P half streamed once,
    //    VT slice (2.1 MB) L2-resident.
    gemm_nt<2, false><<<dim3(512), blk, 0, stream>>>(
        (unsigned short*)S, (unsigned short*)S + 2048, VT_h, VT_l,
        out, Opart1, 4, 16, 16, L, 4096, L, C, 1.0f, (long)L * 4096, LC, LC);

    // 7) O = partial0 + partial1 -> hi/lo over dead Q
    reduce_hl<<<dim3((unsigned)(n4 / 256)), blk, 0, stream>>>(out, Opart1, O_h, O_l);

    // 8) final projection split-K2: 512 blocks; n-inner. NT=4, MT=64, ZT=2, ML=16.
    gemm_nt<2, false><<<dim3(512), blk, 0, stream>>>(O_h, O_l, WoT_h, WoT_l,
        Fp0, Fp1, 4, 64, 16, C, C, C, C, 1.0f, 0, 0, 0);

    // 9) out = Fp0 + Fp1 + bo
    reduce_bias_f32<<<dim3((unsigned)(n4 / 256)), blk, 0, stream>>>(Fp0, Fp1, bo, out);
}

// Round 6
// 251.063 us; speedup vs baseline: 4.7693x; 1.3862x over previous
//
#include <hip/hip_runtime.h>
#include <math.h>

typedef __attribute__((ext_vector_type(8))) short bf16x8;
typedef __attribute__((ext_vector_type(4))) float f32x4;

__device__ __forceinline__ unsigned short f2bf(float x) {
    union { float f; unsigned u; } v; v.f = x;
    unsigned r = v.u + 0x7FFFu + ((v.u >> 16) & 1u);   // RNE
    return (unsigned short)(r >> 16);
}

// XCD-aware tile decode (R4-verified): blocks sharing an A-strip land on the
// same XCD and adjacent in schedule order -> shared operand served from L2.
template<bool M_INNER>
__device__ __forceinline__ void tile_decode(int id, int NT, int MT, int ML,
                                            int& m, int& n, int& zz)
{
    const int xcd = id & 7;
    const int s = id >> 3;
    int mloc;
    if (M_INNER) { mloc = s % ML; n = s / ML; }
    else         { n = s % NT;   mloc = s / NT; }
    const int g = xcd * ML + mloc;
    m = g % MT;
    zz = g / MT;
}

// Async global->LDS staging of a 128x32 bf16 tile (8 KB) with width=16 DMA.
// LDS dest semantics: wave-uniform base + lane*16 [m97/m104-verified].
// Segment = 16 rows x 32 cols = 1 KB; lane i covers row seg*16+(i>>2),
// cols [(i&3)*8, +8). 8 segments; wave w issues segs 2w, 2w+1.
__device__ __forceinline__ void stage_tile(const unsigned short* g, long lda,
                                           unsigned short* lds, int wave, int lane)
{
    #pragma unroll
    for (int s = 0; s < 2; ++s) {
        const int seg = wave * 2 + s;
        const unsigned short* gp = g + (long)(seg * 16 + (lane >> 2)) * lda + (lane & 3) * 8;
        __builtin_amdgcn_global_load_lds(
            (const __attribute__((address_space(1))) void*)gp,
            (__attribute__((address_space(3))) void*)(lds + seg * 512),
            16, 0, 0);
    }
}

// ---------------------------------------------------------------------------
// 3 input tensors -> bf16 (hi only), one dispatch.
struct Split3Args {
    const float* src[3];
    unsigned short* dh[3];
};
__global__ __launch_bounds__(256)
void split_rows3(Split3Args a, long n4)
{
    const int z = blockIdx.z;
    long i = (long)blockIdx.x * 256 + threadIdx.x;
    if (i >= n4) return;
    float4 v = ((const float4*)a.src[z])[i];
    ushort4 h;
    h.x = f2bf(v.x); h.y = f2bf(v.y); h.z = f2bf(v.z); h.w = f2bf(v.w);
    ((ushort4*)a.dh[z])[i] = h;
}

// ---------------------------------------------------------------------------
// 4 weights [512][512] fp32 -> transposed bf16 (hi only), one dispatch.
struct WT4Args {
    const float* src[4];
    unsigned short* dh[4];
};
__global__ __launch_bounds__(256)
void wtrans4(WT4Args a)
{
    __shared__ float T[32][33];
    const int z = blockIdx.z;
    const int Cc = 512, R = 512;
    const float* s = a.src[z];
    const int r0 = blockIdx.y * 32, c0 = blockIdx.x * 32;
    const int t = threadIdx.x;
    {
        const int r = t >> 3, cq = (t & 7) * 4;
        float4 v = *(const float4*)(s + (long)(r0 + r) * Cc + c0 + cq);
        T[r][cq] = v.x; T[r][cq + 1] = v.y; T[r][cq + 2] = v.z; T[r][cq + 3] = v.w;
    }
    __syncthreads();
    {
        const int c = t >> 3, rq = (t & 7) * 4;
        ushort4 h;
        h.x = f2bf(T[rq][c]); h.y = f2bf(T[rq + 1][c]);
        h.z = f2bf(T[rq + 2][c]); h.w = f2bf(T[rq + 3][c]);
        *(ushort4*)(a.dh[z] + (long)(c0 + c) * R + r0 + rq) = h;
    }
}

// ---------------------------------------------------------------------------
// Merged Q/K/V projection, 1-term bf16 MFMA. 768 blocks, n-inner decode
// (NT=4, MT=64, ZT=3, ML=24). z<2: bf16 out [M][512]; z==2: transposed
// VT[b][col][l] out (C/D layout gives 4 consecutive rows/lane -> ushort4).
struct ProjArgs {
    const unsigned short* Ah[3];
    const unsigned short* Bh[3];
    const float* bias[3];
    unsigned short* Ch[3];
};
__global__ __launch_bounds__(256)
void proj_gemm(ProjArgs pa)
{
    __shared__ __align__(16) unsigned short Ah[128 * 32];
    __shared__ __align__(16) unsigned short Bh[128 * 32];

    int mt, nt, z;
    tile_decode<false>(blockIdx.x, 4, 64, 24, mt, nt, z);

    const unsigned short* pAh = pa.Ah[z];
    const unsigned short* pBh = pa.Bh[z];
    const float* bias = pa.bias[z];

    const int tid = threadIdx.x;
    const int m0 = mt * 128, n0 = nt * 128;
    const int wave = tid >> 6, lane = tid & 63;
    const int wr = wave >> 1, wc = wave & 1;
    const int quad = lane >> 4, mr = lane & 15;

    f32x4 acc[4][4] = {};

    for (int k0 = 0; k0 < 512; k0 += 32) {
        stage_tile(pAh + (long)m0 * 512 + k0, 512, Ah, wave, lane);
        stage_tile(pBh + (long)n0 * 512 + k0, 512, Bh, wave, lane);
        __syncthreads();

        bf16x8 af[4], bf[4];
        #pragma unroll
        for (int r = 0; r < 4; ++r)
            af[r] = *(const bf16x8*)&Ah[(wr * 64 + r * 16 + mr) * 32 + quad * 8];
        #pragma unroll
        for (int c = 0; c < 4; ++c)
            bf[c] = *(const bf16x8*)&Bh[(wc * 64 + c * 16 + mr) * 32 + quad * 8];
        #pragma unroll
        for (int r = 0; r < 4; ++r)
            #pragma unroll
            for (int c = 0; c < 4; ++c)
                acc[r][c] = __builtin_amdgcn_mfma_f32_16x16x32_bf16(af[r], bf[c], acc[r][c], 0, 0, 0);
        __syncthreads();
    }

    if (z < 2) {
        unsigned short* Chi = pa.Ch[z];
        #pragma unroll
        for (int r = 0; r < 4; ++r)
            #pragma unroll
            for (int c = 0; c < 4; ++c) {
                const int col = n0 + wc * 64 + c * 16 + mr;
                const float bv = bias[col];
                #pragma unroll
                for (int e = 0; e < 4; ++e) {
                    const int rowg = m0 + wr * 64 + r * 16 + quad * 4 + e;
                    Chi[(long)rowg * 512 + col] = f2bf(acc[r][c][e] + bv);
                }
            }
    } else {
        unsigned short* VTh = pa.Ch[2];
        #pragma unroll
        for (int r = 0; r < 4; ++r)
            #pragma unroll
            for (int c = 0; c < 4; ++c) {
                const int col = n0 + wc * 64 + c * 16 + mr;
                const float bv = bias[col];
                const int rowg0 = m0 + wr * 64 + r * 16 + quad * 4;
                const int b = rowg0 >> 11, l0 = rowg0 & 2047;
                ushort4 hv;
                hv.x = f2bf(acc[r][c][0] + bv);
                hv.y = f2bf(acc[r][c][1] + bv);
                hv.z = f2bf(acc[r][c][2] + bv);
                hv.w = f2bf(acc[r][c][3] + bv);
                *(ushort4*)(VTh + (long)b * (512 * 2048) + (long)col * 2048 + l0) = hv;
            }
    }
}

// ---------------------------------------------------------------------------
// 1-term bf16 MFMA GEMM, NT, fp32 out. 1-D grid, XCD decode.
// KSPLIT=2: zz = batch*2 + ks; partial -> Cf0/Cf1.
template<int KSPLIT, bool M_INNER>
__global__ __launch_bounds__(256)
void gemm1(const unsigned short* __restrict__ Ah_g, const unsigned short* __restrict__ Bh_g,
           float* __restrict__ Cf0, float* __restrict__ Cf1,
           int NT, int MT, int ML, int K,
           long lda, long ldb, long ldc, float alpha,
           long sA, long sB, long sC)
{
    __shared__ __align__(16) unsigned short Ah[128 * 32];
    __shared__ __align__(16) unsigned short Bh[128 * 32];

    int mt, nt, zz;
    tile_decode<M_INNER>(blockIdx.x, NT, MT, ML, mt, nt, zz);

    const int tid = threadIdx.x;
    const int m0 = mt * 128, n0 = nt * 128;
    const long zb = (KSPLIT == 2) ? (zz >> 1) : zz;
    const int ks = (KSPLIT == 2) ? (zz & 1) : 0;
    const int kh = K / KSPLIT;
    const int k_begin = ks * kh, k_end = k_begin + kh;
    float* Cf = (ks == 0) ? Cf0 : Cf1;

    const unsigned short* pAh = Ah_g + zb * sA + (long)m0 * lda;
    const unsigned short* pBh = Bh_g + zb * sB + (long)n0 * ldb;

    const int wave = tid >> 6, lane = tid & 63;
    const int wr = wave >> 1, wc = wave & 1;
    const int quad = lane >> 4, mr = lane & 15;

    f32x4 acc[4][4] = {};

    for (int k0 = k_begin; k0 < k_end; k0 += 32) {
        stage_tile(pAh + k0, lda, Ah, wave, lane);
        stage_tile(pBh + k0, ldb, Bh, wave, lane);
        __syncthreads();

        bf16x8 af[4], bf[4];
        #pragma unroll
        for (int r = 0; r < 4; ++r)
            af[r] = *(const bf16x8*)&Ah[(wr * 64 + r * 16 + mr) * 32 + quad * 8];
        #pragma unroll
        for (int c = 0; c < 4; ++c)
            bf[c] = *(const bf16x8*)&Bh[(wc * 64 + c * 16 + mr) * 32 + quad * 8];
        #pragma unroll
        for (int r = 0; r < 4; ++r)
            #pragma unroll
            for (int c = 0; c < 4; ++c)
                acc[r][c] = __builtin_amdgcn_mfma_f32_16x16x32_bf16(af[r], bf[c], acc[r][c], 0, 0, 0);
        __syncthreads();
    }

    #pragma unroll
    for (int r = 0; r < 4; ++r)
        #pragma unroll
        for (int c = 0; c < 4; ++c) {
            const int col = n0 + wc * 64 + c * 16 + mr;
            #pragma unroll
            for (int e = 0; e < 4; ++e) {
                const int rowg = m0 + wr * 64 + r * 16 + quad * 4 + e;
                Cf[zb * sC + (long)rowg * ldc + col] = acc[r][c][e] * alpha;
            }
        }
}

// ---------------------------------------------------------------------------
// Softmax over rows of 2048 fp32; P written as bf16 IN PLACE over bytes
// [0,4096) of the row (row pitch stays 8192 B).
__global__ __launch_bounds__(256)
void softmax_rows_h(float* __restrict__ S)
{
    float* row = S + (long)blockIdx.x * 2048;
    const int tid = threadIdx.x;

    float4 v0 = *(float4*)(row + tid * 4);
    float4 v1 = *(float4*)(row + 1024 + tid * 4);
    float x[8] = { v0.x, v0.y, v0.z, v0.w, v1.x, v1.y, v1.z, v1.w };

    __shared__ float red[4];

    float lm = x[0];
    #pragma unroll
    for (int i = 1; i < 8; ++i) lm = fmaxf(lm, x[i]);
    #pragma unroll
    for (int off = 32; off > 0; off >>= 1) lm = fmaxf(lm, __shfl_down(lm, off));
    if ((tid & 63) == 0) red[tid >> 6] = lm;
    __syncthreads();
    if (tid == 0) red[0] = fmaxf(fmaxf(red[0], red[1]), fmaxf(red[2], red[3]));
    __syncthreads();
    const float rowmax = red[0];
    __syncthreads();

    float ls = 0.f;
    #pragma unroll
    for (int i = 0; i < 8; ++i) { x[i] = __expf(x[i] - rowmax); ls += x[i]; }
    #pragma unroll
    for (int off = 32; off > 0; off >>= 1) ls += __shfl_down(ls, off);
    if ((tid & 63) == 0) red[tid >> 6] = ls;
    __syncthreads();
    if (tid == 0) red[0] = red[0] + red[1] + red[2] + red[3];
    __syncthreads();
    const float inv = 1.0f / red[0];

    unsigned short* ph = (unsigned short*)row;
    ushort4 h0, h1;
    h0.x = f2bf(x[0] * inv); h0.y = f2bf(x[1] * inv);
    h0.z = f2bf(x[2] * inv); h0.w = f2bf(x[3] * inv);
    h1.x = f2bf(x[4] * inv); h1.y = f2bf(x[5] * inv);
    h1.z = f2bf(x[6] * inv); h1.w = f2bf(x[7] * inv);
    *(ushort4*)(ph + tid * 4) = h0;
    *(ushort4*)(ph + 1024 + tid * 4) = h1;
}

// ---------------------------------------------------------------------------
// O = p0 + p1 -> bf16
__global__ __launch_bounds__(256)
void reduce_o(const float* __restrict__ p0, const float* __restrict__ p1,
              unsigned short* __restrict__ oh)
{
    long i = (long)blockIdx.x * 256 + threadIdx.x;
    float4 a = ((const float4*)p0)[i];
    float4 b = ((const float4*)p1)[i];
    ushort4 h;
    h.x = f2bf(a.x + b.x); h.y = f2bf(a.y + b.y);
    h.z = f2bf(a.z + b.z); h.w = f2bf(a.w + b.w);
    ((ushort4*)oh)[i] = h;
}

// out = p0 + p1 + bias (row length 512 floats = 128 float4)
__global__ __launch_bounds__(256)
void reduce_bias_f32(const float* __restrict__ p0, const float* __restrict__ p1,
                     const float* __restrict__ bias, float* __restrict__ out)
{
    long i = (long)blockIdx.x * 256 + threadIdx.x;
    float4 a = ((const float4*)p0)[i];
    float4 b = ((const float4*)p1)[i];
    float4 bb = ((const float4*)bias)[i & 127];
    ((float4*)out)[i] = make_float4(a.x + b.x + bb.x, a.y + b.y + bb.y,
                                    a.z + b.z + bb.z, a.w + b.w + bb.w);
}

// ---------------------------------------------------------------------------
extern "C" void kernel_launch(void* const* d_in, const int* in_sizes, int n_in,
                              void* d_out, int out_size, void* d_ws, size_t ws_size,
                              hipStream_t stream) {
    const float* query = (const float*)d_in[0];
    const float* key   = (const float*)d_in[1];
    const float* value = (const float*)d_in[2];
    const float* Wq    = (const float*)d_in[3];
    const float* bq    = (const float*)d_in[4];
    const float* Wk    = (const float*)d_in[5];
    const float* bk    = (const float*)d_in[6];
    const float* Wv    = (const float*)d_in[7];
    const float* bv    = (const float*)d_in[8];
    const float* Wo    = (const float*)d_in[9];
    const float* bo    = (const float*)d_in[10];
    float* out = (float*)d_out;

    const int B = 4, L = 2048, C = 512;
    const int M = B * L;               // 8192
    char* ws = (char*)d_ws;

    // ---- workspace map (bytes), total 111,149,056 -------------------------
    // [0, 2.10M):        WT_h x4 (512 KB each)
    // [2.10M, 27.3M):    in q/k/v bf16 (dead after proj)
    // [2.10M, 69.2M):    S fp32 67 MB (overlays inputs after proj);
    //                    after PV: Fp0/Fp1 final-proj partials live here
    // [69.2M, 77.6M):    VT_h
    // [77.6M, 86.0M):    Q_h  -> O_h after reduce_o
    // [86.0M, 94.4M):    K_h
    // [94.4M, 111.1M):   PV partial-1 fp32 (partial-0 -> d_out scratch)
    unsigned short* WqT_h = (unsigned short*)(ws);
    unsigned short* WkT_h = (unsigned short*)(ws + 524288);
    unsigned short* WvT_h = (unsigned short*)(ws + 1048576);
    unsigned short* WoT_h = (unsigned short*)(ws + 1572864);
    unsigned short* inq_h = (unsigned short*)(ws + 2097152);
    unsigned short* ink_h = (unsigned short*)(ws + 10485760);
    unsigned short* inv_h = (unsigned short*)(ws + 18874368);
    float*          S     = (float*)(ws + 2097152);
    float*          Fp0   = (float*)(ws + 2097152);
    float*          Fp1   = (float*)(ws + 18874368);
    unsigned short* VT_h  = (unsigned short*)(ws + 69206016);
    unsigned short* Q_h   = (unsigned short*)(ws + 77594624);
    unsigned short* K_h   = (unsigned short*)(ws + 85983232);
    float*          Opart1 = (float*)(ws + 94371840);
    unsigned short* O_h   = Q_h;   // Q dead after QK^T

    const dim3 blk(256);
    const float scale = 1.0f / sqrtf((float)C);
    const long LC = (long)L * C;      // 1,048,576
    const long LL = (long)L * L;      // 4,194,304

    // 1) weight transposes -> bf16 (one dispatch)
    WT4Args wt;
    wt.src[0] = Wq; wt.src[1] = Wk; wt.src[2] = Wv; wt.src[3] = Wo;
    wt.dh[0] = WqT_h; wt.dh[1] = WkT_h; wt.dh[2] = WvT_h; wt.dh[3] = WoT_h;
    wtrans4<<<dim3(16, 16, 4), blk, 0, stream>>>(wt);

    // 2) input -> bf16 (one dispatch)
    const long n4 = (long)M * C / 4;   // 1,048,576
    Split3Args sp;
    sp.src[0] = query; sp.src[1] = key; sp.src[2] = value;
    sp.dh[0] = inq_h; sp.dh[1] = ink_h; sp.dh[2] = inv_h;
    split_rows3<<<dim3((unsigned)((n4 + 255) / 256), 1, 3), blk, 0, stream>>>(sp, n4);

    // 3) merged projections (768 blocks, XCD decode NT=4, MT=64, ML=24)
    ProjArgs pa;
    pa.Ah[0] = inq_h; pa.Bh[0] = WqT_h; pa.bias[0] = bq; pa.Ch[0] = Q_h;
    pa.Ah[1] = ink_h; pa.Bh[1] = WkT_h; pa.bias[1] = bk; pa.Ch[1] = K_h;
    pa.Ah[2] = inv_h; pa.Bh[2] = WvT_h; pa.bias[2] = bv; pa.Ch[2] = VT_h;
    proj_gemm<<<dim3(768), blk, 0, stream>>>(pa);

    // 4) S = scale * Q @ K^T. 1024 blocks, m-inner (NT=16, MT=16, ML=8)
    gemm1<1, true><<<dim3(1024), blk, 0, stream>>>(Q_h, K_h, S, nullptr,
        16, 16, 8, C, 512, 512, 2048, scale, LC, LC, LL);

    // 5) softmax -> P bf16 in place (first 4 KB of each 8 KB row)
    softmax_rows_h<<<dim3(M), blk, 0, stream>>>(S);

    // 6) PV split-K2: 512 blocks, n-inner (NT=4, MT=16, ML=16); partials to
    //    d_out (ks=0) and Opart1 (ks=1)
    gemm1<2, false><<<dim3(512), blk, 0, stream>>>(
        (unsigned short*)S, VT_h, out, Opart1,
        4, 16, 16, L, 4096, 2048, 512, 1.0f, (long)L * 4096, LC, LC);

    // 7) O = partial0 + partial1 -> bf16 over dead Q
    reduce_o<<<dim3((unsigned)(n4 / 256)), blk, 0, stream>>>(out, Opart1, O_h);

    // 8) final projection split-K2: 512 blocks, n-inner (NT=4, MT=64, ML=16)
    gemm1<2, false><<<dim3(512), blk, 0, stream>>>(O_h, WoT_h, Fp0, Fp1,
        4, 64, 16, C, 512, 512, 512, 1.0f, 0, 0, 0);

    // 9) out = Fp0 + Fp1 + bo
    reduce_bias_f32<<<dim3((unsigned)(n4 / 256)), blk, 0, stream>>>(Fp0, Fp1, bo, out);
}

// Round 7
// 226.081 us; speedup vs baseline: 5.2963x; 1.1105x over previous
//
#include <hip/hip_runtime.h>
#include <hip/hip_fp16.h>
#include <math.h>

typedef __attribute__((ext_vector_type(8))) short bf16x8;
typedef __attribute__((ext_vector_type(4))) float f32x4;

__device__ __forceinline__ unsigned short f2bf(float x) {
    union { float f; unsigned u; } v; v.f = x;
    unsigned r = v.u + 0x7FFFu + ((v.u >> 16) & 1u);   // RNE
    return (unsigned short)(r >> 16);
}
__device__ __forceinline__ unsigned short f2h(float x) {
    union { __half h; unsigned short u; } v; v.h = __float2half(x); return v.u;
}
__device__ __forceinline__ float h2f(unsigned short u) {
    union { __half h; unsigned short u; } v; v.u = u; return __half2float(v.h);
}

// XCD-aware tile decode (R4-verified).
template<bool M_INNER>
__device__ __forceinline__ void tile_decode(int id, int NT, int MT, int ML,
                                            int& m, int& n, int& zz)
{
    const int xcd = id & 7;
    const int s = id >> 3;
    int mloc;
    if (M_INNER) { mloc = s % ML; n = s / ML; }
    else         { n = s % NT;   mloc = s / NT; }
    const int g = xcd * ML + mloc;
    m = g % MT;
    zz = g / MT;
}

// Async global->LDS staging of a ROWSx64 bf16 tile, 16B DMA, XOR-swizzled:
// LDS slot cc (8-half chunk) of row R holds global chunk cc ^ (R&7).
// Reads of chunk q at row R use slot q ^ (R&7) -> bank-conflict-free
// (2-way, free per m136) despite the DMA's fixed lane*16 layout.
template<int ROWS>
__device__ __forceinline__ void stage64(const unsigned short* g, long lda,
                                        unsigned short* lds, int wave, int lane)
{
    const int rr = lane >> 3, cc = lane & 7;
    const int ccg = (cc ^ rr) * 8;
    #pragma unroll
    for (int s = 0; s < ROWS / 32; ++s) {
        const int seg = wave * (ROWS / 32) + s;
        const unsigned short* gp = g + (long)(seg * 8 + rr) * lda + ccg;
        __builtin_amdgcn_global_load_lds(
            (const __attribute__((address_space(1))) void*)gp,
            (__attribute__((address_space(3))) void*)(lds + seg * 512),
            16, 0, 0);
    }
}

// ---------------------------------------------------------------------------
// 3 input tensors -> bf16, one dispatch.
struct Split3Args {
    const float* src[3];
    unsigned short* dh[3];
};
__global__ __launch_bounds__(256)
void split_rows3(Split3Args a, long n4)
{
    const int z = blockIdx.z;
    long i = (long)blockIdx.x * 256 + threadIdx.x;
    if (i >= n4) return;
    float4 v = ((const float4*)a.src[z])[i];
    ushort4 h;
    h.x = f2bf(v.x); h.y = f2bf(v.y); h.z = f2bf(v.z); h.w = f2bf(v.w);
    ((ushort4*)a.dh[z])[i] = h;
}

// ---------------------------------------------------------------------------
// 4 weights [512][512] fp32 -> transposed bf16, one dispatch.
struct WT4Args {
    const float* src[4];
    unsigned short* dh[4];
};
__global__ __launch_bounds__(256)
void wtrans4(WT4Args a)
{
    __shared__ float T[32][33];
    const int z = blockIdx.z;
    const int Cc = 512, R = 512;
    const float* s = a.src[z];
    const int r0 = blockIdx.y * 32, c0 = blockIdx.x * 32;
    const int t = threadIdx.x;
    {
        const int r = t >> 3, cq = (t & 7) * 4;
        float4 v = *(const float4*)(s + (long)(r0 + r) * Cc + c0 + cq);
        T[r][cq] = v.x; T[r][cq + 1] = v.y; T[r][cq + 2] = v.z; T[r][cq + 3] = v.w;
    }
    __syncthreads();
    {
        const int c = t >> 3, rq = (t & 7) * 4;
        ushort4 h;
        h.x = f2bf(T[rq][c]); h.y = f2bf(T[rq + 1][c]);
        h.z = f2bf(T[rq + 2][c]); h.w = f2bf(T[rq + 3][c]);
        *(ushort4*)(a.dh[z] + (long)(c0 + c) * R + r0 + rq) = h;
    }
}

// ---------------------------------------------------------------------------
// Merged Q/K/V projection, 128x128 tile, BK=64, swizzled DMA staging.
struct ProjArgs {
    const unsigned short* Ah[3];
    const unsigned short* Bh[3];
    const float* bias[3];
    unsigned short* Ch[3];
};
__global__ __launch_bounds__(256)
void proj_gemm(ProjArgs pa)
{
    __shared__ __align__(16) unsigned short smA[128 * 64];
    __shared__ __align__(16) unsigned short smB[128 * 64];

    int mt, nt, z;
    tile_decode<false>(blockIdx.x, 4, 64, 24, mt, nt, z);

    const unsigned short* pAh = pa.Ah[z] + (long)(mt * 128) * 512;
    const unsigned short* pBh = pa.Bh[z] + (long)(nt * 128) * 512;
    const float* bias = pa.bias[z];

    const int tid = threadIdx.x;
    const int m0 = mt * 128, n0 = nt * 128;
    const int wave = tid >> 6, lane = tid & 63;
    const int wr = wave >> 1, wc = wave & 1;
    const int quad = lane >> 4, mr = lane & 15;
    const int sw = mr & 7;

    f32x4 acc[4][4] = {};

    for (int k0 = 0; k0 < 512; k0 += 64) {
        stage64<128>(pAh + k0, 512, smA, wave, lane);
        stage64<128>(pBh + k0, 512, smB, wave, lane);
        __syncthreads();
        #pragma unroll
        for (int h = 0; h < 2; ++h) {
            const int q2 = (h << 2) | quad;
            bf16x8 af[4], bf[4];
            #pragma unroll
            for (int r = 0; r < 4; ++r)
                af[r] = *(const bf16x8*)&smA[(wr * 64 + r * 16 + mr) * 64 + ((q2 ^ sw) << 3)];
            #pragma unroll
            for (int c = 0; c < 4; ++c)
                bf[c] = *(const bf16x8*)&smB[(wc * 64 + c * 16 + mr) * 64 + ((q2 ^ sw) << 3)];
            #pragma unroll
            for (int r = 0; r < 4; ++r)
                #pragma unroll
                for (int c = 0; c < 4; ++c)
                    acc[r][c] = __builtin_amdgcn_mfma_f32_16x16x32_bf16(af[r], bf[c], acc[r][c], 0, 0, 0);
        }
        __syncthreads();
    }

    if (z < 2) {
        unsigned short* Chi = pa.Ch[z];
        #pragma unroll
        for (int r = 0; r < 4; ++r)
            #pragma unroll
            for (int c = 0; c < 4; ++c) {
                const int col = n0 + wc * 64 + c * 16 + mr;
                const float bv = bias[col];
                #pragma unroll
                for (int e = 0; e < 4; ++e) {
                    const int rowg = m0 + wr * 64 + r * 16 + quad * 4 + e;
                    Chi[(long)rowg * 512 + col] = f2bf(acc[r][c][e] + bv);
                }
            }
    } else {
        // transposed: VT[b][col][l]; C/D layout's 4 consecutive rows -> ushort4
        unsigned short* VTh = pa.Ch[2];
        #pragma unroll
        for (int r = 0; r < 4; ++r)
            #pragma unroll
            for (int c = 0; c < 4; ++c) {
                const int col = n0 + wc * 64 + c * 16 + mr;
                const float bv = bias[col];
                const int rowg0 = m0 + wr * 64 + r * 16 + quad * 4;
                const int b = rowg0 >> 11, l0 = rowg0 & 2047;
                ushort4 hv;
                hv.x = f2bf(acc[r][c][0] + bv);
                hv.y = f2bf(acc[r][c][1] + bv);
                hv.z = f2bf(acc[r][c][2] + bv);
                hv.w = f2bf(acc[r][c][3] + bv);
                *(ushort4*)(VTh + (long)b * (512 * 2048) + (long)col * 2048 + l0) = hv;
            }
    }
}

// ---------------------------------------------------------------------------
// QK^T: S(fp16) = scale * Q @ K^T. 128x128 tile, BK=64, swizzled staging,
// LDS-transposed coalesced fp16 epilogue. Grid 1024, m-inner decode.
union QKTSmem {
    unsigned short stage[2][128 * 64];   // 32 KB staging
    unsigned short ep[128 * 132];        // 33.8 KB epilogue transpose
};
__global__ __launch_bounds__(256)
void qkt_gemm(const unsigned short* __restrict__ Qg, const unsigned short* __restrict__ Kg,
              unsigned short* __restrict__ Sg, float alpha)
{
    __shared__ __align__(16) QKTSmem sm;

    int mt, nt, zz;
    tile_decode<true>(blockIdx.x, 16, 16, 8, mt, nt, zz);

    const int tid = threadIdx.x;
    const int m0 = mt * 128, n0 = nt * 128;
    const long LC = 2048L * 512;
    const unsigned short* pA = Qg + (long)zz * LC + (long)m0 * 512;
    const unsigned short* pB = Kg + (long)zz * LC + (long)n0 * 512;

    const int wave = tid >> 6, lane = tid & 63;
    const int wr = wave >> 1, wc = wave & 1;
    const int quad = lane >> 4, mr = lane & 15;
    const int sw = mr & 7;

    f32x4 acc[4][4] = {};

    for (int k0 = 0; k0 < 512; k0 += 64) {
        stage64<128>(pA + k0, 512, sm.stage[0], wave, lane);
        stage64<128>(pB + k0, 512, sm.stage[1], wave, lane);
        __syncthreads();
        #pragma unroll
        for (int h = 0; h < 2; ++h) {
            const int q2 = (h << 2) | quad;
            bf16x8 af[4], bf[4];
            #pragma unroll
            for (int r = 0; r < 4; ++r)
                af[r] = *(const bf16x8*)&sm.stage[0][(wr * 64 + r * 16 + mr) * 64 + ((q2 ^ sw) << 3)];
            #pragma unroll
            for (int c = 0; c < 4; ++c)
                bf[c] = *(const bf16x8*)&sm.stage[1][(wc * 64 + c * 16 + mr) * 64 + ((q2 ^ sw) << 3)];
            #pragma unroll
            for (int r = 0; r < 4; ++r)
                #pragma unroll
                for (int c = 0; c < 4; ++c)
                    acc[r][c] = __builtin_amdgcn_mfma_f32_16x16x32_bf16(af[r], bf[c], acc[r][c], 0, 0, 0);
        }
        __syncthreads();
    }

    // epilogue: acc -> LDS (fp16, transposing the C/D layout) -> coalesced 16B stores
    #pragma unroll
    for (int r = 0; r < 4; ++r)
        #pragma unroll
        for (int c = 0; c < 4; ++c) {
            const int col = wc * 64 + c * 16 + mr;
            #pragma unroll
            for (int e = 0; e < 4; ++e) {
                const int rowl = wr * 64 + r * 16 + quad * 4 + e;
                sm.ep[rowl * 132 + col] = f2h(acc[r][c][e] * alpha);
            }
        }
    __syncthreads();
    {
        const int R = tid >> 1, hh = tid & 1;
        const unsigned short* src = &sm.ep[R * 132 + hh * 64];
        unsigned short* dst = Sg + (long)zz * (2048L * 2048) + (long)(m0 + R) * 2048 + n0 + hh * 64;
        #pragma unroll
        for (int j = 0; j < 8; ++j)
            *(bf16x8*)(dst + j * 8) = *(const bf16x8*)(src + j * 8);
    }
}

// ---------------------------------------------------------------------------
// Softmax over rows of 2048 fp16; writes P as bf16 IN PLACE (same 4 KB row).
__global__ __launch_bounds__(256)
void softmax_h2b(unsigned short* __restrict__ S)
{
    unsigned short* row = S + (long)blockIdx.x * 2048;
    const int tid = threadIdx.x;

    bf16x8 raw = *(bf16x8*)(row + tid * 8);
    float x[8];
    #pragma unroll
    for (int i = 0; i < 8; ++i) x[i] = h2f((unsigned short)raw[i]);

    __shared__ float red[4];

    float lm = x[0];
    #pragma unroll
    for (int i = 1; i < 8; ++i) lm = fmaxf(lm, x[i]);
    #pragma unroll
    for (int off = 32; off > 0; off >>= 1) lm = fmaxf(lm, __shfl_down(lm, off));
    if ((tid & 63) == 0) red[tid >> 6] = lm;
    __syncthreads();
    if (tid == 0) red[0] = fmaxf(fmaxf(red[0], red[1]), fmaxf(red[2], red[3]));
    __syncthreads();
    const float rowmax = red[0];
    __syncthreads();

    float ls = 0.f;
    #pragma unroll
    for (int i = 0; i < 8; ++i) { x[i] = __expf(x[i] - rowmax); ls += x[i]; }
    #pragma unroll
    for (int off = 32; off > 0; off >>= 1) ls += __shfl_down(ls, off);
    if ((tid & 63) == 0) red[tid >> 6] = ls;
    __syncthreads();
    if (tid == 0) red[0] = red[0] + red[1] + red[2] + red[3];
    __syncthreads();
    const float inv = 1.0f / red[0];

    bf16x8 o;
    #pragma unroll
    for (int i = 0; i < 8; ++i) o[i] = (short)f2bf(x[i] * inv);
    *(bf16x8*)(row + tid * 8) = o;
}

// ---------------------------------------------------------------------------
// 64x128-tile GEMM (NT), BK=64, no split-K. 4 waves each own 64x32.
// BF16_OUT: bf16 out (PV -> O). else fp32 out + bias (final projection).
template<bool BF16_OUT>
__global__ __launch_bounds__(256)
void gemm64(const unsigned short* __restrict__ Ag, const unsigned short* __restrict__ Bg,
            unsigned short* __restrict__ Cbf, float* __restrict__ Cf,
            const float* __restrict__ bias,
            int NT, int MT, int ML, int K,
            long lda, long ldb, long ldc, long sA, long sB, long sC)
{
    __shared__ __align__(16) unsigned short smA[64 * 64];
    __shared__ __align__(16) unsigned short smB[128 * 64];

    int mt, nt, zz;
    tile_decode<false>(blockIdx.x, NT, MT, ML, mt, nt, zz);

    const int tid = threadIdx.x;
    const int m0 = mt * 64, n0 = nt * 128;
    const unsigned short* pA = Ag + zz * sA + (long)m0 * lda;
    const unsigned short* pB = Bg + zz * sB + (long)n0 * ldb;

    const int wave = tid >> 6, lane = tid & 63;
    const int quad = lane >> 4, mr = lane & 15;
    const int sw = mr & 7;

    f32x4 acc[4][2] = {};

    for (int k0 = 0; k0 < K; k0 += 64) {
        stage64<64>(pA + k0, lda, smA, wave, lane);
        stage64<128>(pB + k0, ldb, smB, wave, lane);
        __syncthreads();
        #pragma unroll
        for (int h = 0; h < 2; ++h) {
            const int q2 = (h << 2) | quad;
            bf16x8 af[4], bf[2];
            #pragma unroll
            for (int r = 0; r < 4; ++r)
                af[r] = *(const bf16x8*)&smA[(r * 16 + mr) * 64 + ((q2 ^ sw) << 3)];
            #pragma unroll
            for (int c = 0; c < 2; ++c)
                bf[c] = *(const bf16x8*)&smB[(wave * 32 + c * 16 + mr) * 64 + ((q2 ^ sw) << 3)];
            #pragma unroll
            for (int r = 0; r < 4; ++r)
                #pragma unroll
                for (int c = 0; c < 2; ++c)
                    acc[r][c] = __builtin_amdgcn_mfma_f32_16x16x32_bf16(af[r], bf[c], acc[r][c], 0, 0, 0);
        }
        __syncthreads();
    }

    #pragma unroll
    for (int r = 0; r < 4; ++r)
        #pragma unroll
        for (int c = 0; c < 2; ++c) {
            const int col = n0 + wave * 32 + c * 16 + mr;
            const float bv = bias ? bias[col] : 0.0f;
            #pragma unroll
            for (int e = 0; e < 4; ++e) {
                const int rowg = m0 + r * 16 + quad * 4 + e;
                const float v = acc[r][c][e] + bv;
                if (BF16_OUT) Cbf[zz * sC + (long)rowg * ldc + col] = f2bf(v);
                else          Cf [zz * sC + (long)rowg * ldc + col] = v;
            }
        }
}

// ---------------------------------------------------------------------------
extern "C" void kernel_launch(void* const* d_in, const int* in_sizes, int n_in,
                              void* d_out, int out_size, void* d_ws, size_t ws_size,
                              hipStream_t stream) {
    const float* query = (const float*)d_in[0];
    const float* key   = (const float*)d_in[1];
    const float* value = (const float*)d_in[2];
    const float* Wq    = (const float*)d_in[3];
    const float* bq    = (const float*)d_in[4];
    const float* Wk    = (const float*)d_in[5];
    const float* bk    = (const float*)d_in[6];
    const float* Wv    = (const float*)d_in[7];
    const float* bv    = (const float*)d_in[8];
    const float* Wo    = (const float*)d_in[9];
    const float* bo    = (const float*)d_in[10];
    float* out = (float*)d_out;

    const int B = 4, L = 2048, C = 512;
    const int M = B * L;               // 8192
    char* ws = (char*)d_ws;

    // ---- workspace map (bytes), total 94,371,840 --------------------------
    // [0, 2.10M):        WT_h x4
    // [2.10M, 27.3M):    in q/k/v bf16 (dead after proj)
    // [27.3M, 60.8M):    S fp16 33.5 MB -> P bf16 in place
    // [60.8M, 69.2M):    VT_h    [69.2M, 77.6M): Q_h
    // [77.6M, 86.0M):    K_h     [86.0M, 94.4M): O_h
    unsigned short* WqT_h = (unsigned short*)(ws);
    unsigned short* WkT_h = (unsigned short*)(ws + 524288);
    unsigned short* WvT_h = (unsigned short*)(ws + 1048576);
    unsigned short* WoT_h = (unsigned short*)(ws + 1572864);
    unsigned short* inq_h = (unsigned short*)(ws + 2097152);
    unsigned short* ink_h = (unsigned short*)(ws + 10485760);
    unsigned short* inv_h = (unsigned short*)(ws + 18874368);
    unsigned short* S     = (unsigned short*)(ws + 27262976);
    unsigned short* VT_h  = (unsigned short*)(ws + 60817408);
    unsigned short* Q_h   = (unsigned short*)(ws + 69206016);
    unsigned short* K_h   = (unsigned short*)(ws + 77594624);
    unsigned short* O_h   = (unsigned short*)(ws + 85983232);

    const dim3 blk(256);
    const float scale = 1.0f / sqrtf((float)C);
    const long LC = (long)L * C;      // 1,048,576
    const long LL = (long)L * L;      // 4,194,304

    // 1) weight transposes -> bf16
    WT4Args wt;
    wt.src[0] = Wq; wt.src[1] = Wk; wt.src[2] = Wv; wt.src[3] = Wo;
    wt.dh[0] = WqT_h; wt.dh[1] = WkT_h; wt.dh[2] = WvT_h; wt.dh[3] = WoT_h;
    wtrans4<<<dim3(16, 16, 4), blk, 0, stream>>>(wt);

    // 2) inputs -> bf16
    const long n4 = (long)M * C / 4;   // 1,048,576
    Split3Args sp;
    sp.src[0] = query; sp.src[1] = key; sp.src[2] = value;
    sp.dh[0] = inq_h; sp.dh[1] = ink_h; sp.dh[2] = inv_h;
    split_rows3<<<dim3((unsigned)((n4 + 255) / 256), 1, 3), blk, 0, stream>>>(sp, n4);

    // 3) merged projections (768 blocks; NT=4, MT=64, ZT=3, ML=24, n-inner)
    ProjArgs pa;
    pa.Ah[0] = inq_h; pa.Bh[0] = WqT_h; pa.bias[0] = bq; pa.Ch[0] = Q_h;
    pa.Ah[1] = ink_h; pa.Bh[1] = WkT_h; pa.bias[1] = bk; pa.Ch[1] = K_h;
    pa.Ah[2] = inv_h; pa.Bh[2] = WvT_h; pa.bias[2] = bv; pa.Ch[2] = VT_h;
    proj_gemm<<<dim3(768), blk, 0, stream>>>(pa);

    // 4) S = scale * Q @ K^T -> fp16 (1024 blocks; m-inner NT=16, MT=16, ML=8)
    qkt_gemm<<<dim3(1024), blk, 0, stream>>>(Q_h, K_h, S, scale);

    // 5) softmax fp16 -> P bf16 in place
    softmax_h2b<<<dim3(M), blk, 0, stream>>>(S);

    // 6) O = P @ V -> bf16 directly (512 blocks; NT=4, MT=32, ZT=4, ML=16)
    gemm64<true><<<dim3(512), blk, 0, stream>>>(S, VT_h, O_h, nullptr, nullptr,
        4, 32, 16, L, 2048, 2048, 512, LL, LC, LC);

    // 7) out = O @ Wo^T + bo, fp32 directly (512 blocks; NT=4, MT=128, ML=16)
    gemm64<false><<<dim3(512), blk, 0, stream>>>(O_h, WoT_h, nullptr, out, bo,
        4, 128, 16, C, 512, 512, 512, 0, 0, 0);
}